// Round 8
// baseline (547.501 us; speedup 1.0000x reference)
//
#include <hip/hip_runtime.h>

#define NK 512
#define ND 64
#define NHW 4096
#define NPIX 131072            // 32*64*64
#define OUT_ELEMS 8388608      // 32*64*64*64
#define RS 68                  // packed row stride (floats): 64 data + sc + 3 pad (272 B)

typedef float f4 __attribute__((ext_vector_type(4)));

// Packed codebook: row k = {cb[k][0..63], sc[k], 3 pad}. Rewritten by vq_prep
// every launch (stream-ordered before vq_main).
__device__ __attribute__((aligned(64))) float cbp[NK * RS];

// ---------------------------------------------------------------------------
// Prep: pack codebook + sc (numpy-pairwise-8 fp32 sum of fl(c_d^2)); zero the
// two loss slots (harness re-poisons d_out/d_ws to 0xAA every replay).
// ---------------------------------------------------------------------------
__global__ __launch_bounds__(256) void vq_prep(const float* __restrict__ cb,
                                               float* __restrict__ losses) {
#pragma clang fp contract(off)
  {
    const int k = blockIdx.x * 256 + threadIdx.x;   // grid 2*256 = 512
    const float* c = cb + (size_t)k * ND;
    float* dst = cbp + (size_t)k * RS;

    f4 v[16];
#pragma unroll
    for (int dq = 0; dq < 16; ++dq) {
      v[dq] = *(const f4*)(c + dq * 4);
      *(f4*)(dst + dq * 4) = v[dq];
    }
    float rr[8];
    rr[0] = v[0][0] * v[0][0]; rr[1] = v[0][1] * v[0][1];
    rr[2] = v[0][2] * v[0][2]; rr[3] = v[0][3] * v[0][3];
    rr[4] = v[1][0] * v[1][0]; rr[5] = v[1][1] * v[1][1];
    rr[6] = v[1][2] * v[1][2]; rr[7] = v[1][3] * v[1][3];
#pragma unroll
    for (int i = 2; i < 16; i += 2) {
      rr[0] += v[i][0] * v[i][0];     rr[1] += v[i][1] * v[i][1];
      rr[2] += v[i][2] * v[i][2];     rr[3] += v[i][3] * v[i][3];
      rr[4] += v[i + 1][0] * v[i + 1][0]; rr[5] += v[i + 1][1] * v[i + 1][1];
      rr[6] += v[i + 1][2] * v[i + 1][2]; rr[7] += v[i + 1][3] * v[i + 1][3];
    }
    dst[64] = ((rr[0] + rr[1]) + (rr[2] + rr[3])) + ((rr[4] + rr[5]) + (rr[6] + rr[7]));
    if (k < 2) losses[k] = 0.f;
  }
}

// ---- asm building blocks -------------------------------------------------
#define F1(B, X)  "v_fmac_f32 v14, v" #B ", v" #X "\n\t"
#define FM1(B, X) "v_mul_f32 v14, v" #B ", v" #X "\n\t"
#define FQ16_(M,b0,b1,b2,b3,b4,b5,b6,b7,b8,b9,bA,bB,bC,bD,bE,bF,            \
                x0,x1,x2,x3,x4,x5,x6,x7,x8,x9,xA,xB,xC,xD,xE,xF)            \
  M(b0,x0) F1(b1,x1) F1(b2,x2) F1(b3,x3) F1(b4,x4) F1(b5,x5) F1(b6,x6)      \
  F1(b7,x7) F1(b8,x8) F1(b9,x9) F1(bA,xA) F1(bB,xB) F1(bC,xC) F1(bD,xD)     \
  F1(bE,xE) F1(bF,xF)
#define FQ16(...) FQ16_(__VA_ARGS__)
#define REGS_P  80,81,82,83,84,85,86,87,88,89,90,91,92,93,94,95
#define REGS_Q  96,97,98,99,100,101,102,103,104,105,106,107,108,109,110,111
#define REGS_R  112,113,114,115,116,117,118,119,120,121,122,123,124,125,126,127
#define REGS_X0 16,17,18,19,20,21,22,23,24,25,26,27,28,29,30,31
#define REGS_X1 32,33,34,35,36,37,38,39,40,41,42,43,44,45,46,47
#define REGS_X2 48,49,50,51,52,53,54,55,56,57,58,59,60,61,62,63
#define REGS_X3 64,65,66,67,68,69,70,71,72,73,74,75,76,77,78,79

#define LDQ(RNG, OFF) "global_load_dwordx4 v[" RNG "], v[8:9], off offset:" OFF "\n\t"
#define LDP(O0,O1,O2,O3)  LDQ("80:83",O0)   LDQ("84:87",O1)   LDQ("88:91",O2)   LDQ("92:95",O3)
#define LDQQ(O0,O1,O2,O3) LDQ("96:99",O0)   LDQ("100:103",O1) LDQ("104:107",O2) LDQ("108:111",O3)
#define LDR(O0,O1,O2,O3)  LDQ("112:115",O0) LDQ("116:119",O1) LDQ("120:123",O2) LDQ("124:127",O3)
#define LSC(REG, OFF) "global_load_dword " REG ", v[8:9], off offset:" OFF "\n\t"
#define XLD(VD)                                          \
  "global_load_dword " VD ", v[8:9], off\n\t"            \
  "v_add_co_u32 v8, vcc, 0x4000, v8\n\t"                 \
  "v_addc_co_u32 v9, vcc, 0, v9, vcc\n\t"
// combine: d2 = fma(a,-2,Sx) + sc; keep-old on (d2>=m), take-new on strict <.
// Code counter lives in v7 (VGPR!) -- R7 used an SGPR here and tripped the
// constant-bus limit (VOP2 cndmask implicitly reads vcc; +SGPR src0 = 2 bus
// reads -> "invalid operand (violates constant bus restrictions)").
#define CMB(SCREG)                                       \
  "v_fma_f32 v13, v14, -2.0, v15\n\t"                    \
  "v_add_f32 v13, " SCREG ", v13\n\t"                    \
  "v_cmp_ge_f32 vcc, v13, %[mm]\n\t"                     \
  "v_cndmask_b32 %[bb], v7, %[bb], vcc\n\t"              \
  "v_cndmask_b32 %[mm], v13, %[mm], vcc\n\t"             \
  "v_add_u32 v7, 1, v7\n\t"

// ---------------------------------------------------------------------------
// Main: lane = pixel. R6 post-mortem: SMEM drains cost ~700 cyc each (K$
// thrash + OOO SMEM forces lgkmcnt(0) -> pipelining structurally capped).
// R7/R8: codebook streamed via uniform-address global_load_dwordx4 (VMEM is
// IN-ORDER per wave [m135], so counted vmcnt waits enable a deep static
// pipeline; uniform address = 1 L1 transaction, broadcast to 64 lanes).
// Ring: 3 quarter-buffers P/Q/R (v80-127, 16 floats each); 13 loads always
// in flight; per-code waits vmcnt(9/9/8/9) -- full ledger:
//   steady outstanding before code c: [D(4c),D(4c+1),sc(c),D(4c+2)] = 13.
//   j0: vmcnt(9) retires D(4c);  16 FMA; issue D(4c+3) into same buffer.
//   j1: vmcnt(9) retires D(4c+1);16 FMA; issue D(4c+4).
//   j2: vmcnt(8) retires sc(c)+D(4c+2); 16 FMA; issue D(4c+5)+sc(c+1).
//   j3: vmcnt(9) retires D(4c+3);16 FMA; issue D(4c+6); combine.
// Buffers rotate q%3; 3-code body (pattern repeats, 85 iters) + tail c=255.
// Regs: v7 code ctr | v8:9 addr | v10-12 sc slots | v13 d2 | v14 acc |
// v15 Sx | v16-79 x | v80-127 P/Q/R | s29 loop ctr.
// K split: waves 0,1 -> codes 0..255; waves 2,3 -> 256..511; same 128
// pixels; 1024 blocks = 4 blocks/CU = 4 waves/SIMD.
// Numerics bit-identical to R6 (passed): v_mul + 63 v_fmac ascending d;
// d2 = fma(a,-2,Sx)+sc; Sx/sc pairwise-8; ascending codes, keep-old on >=
// (strict-< winner); cross-half tie keeps low half = np.argmin. Loss = m.
// ---------------------------------------------------------------------------
__global__ __launch_bounds__(256, 4) void vq_main(const float* __restrict__ x,
                                                  const float* __restrict__ cb,
                                                  float* __restrict__ out,
                                                  float* __restrict__ idx_out,
                                                  float* __restrict__ losses) {
#pragma clang fp contract(off)
  {
    __shared__ float him[128];
    __shared__ int   hii[128];
    __shared__ float red[2];

    const int tid = threadIdx.x;
    const int wv = tid >> 6;                 // 0..3
    const int lane = tid & 63;
    const int pxl = ((wv & 1) << 6) | lane;  // local pixel 0..127
    const int px = blockIdx.x * 128 + pxl;
    const int b = px >> 12;
    const int hw = px & 4095;

    const unsigned long long xa =
        (unsigned long long)(const void*)(x + (size_t)b * (ND * NHW) + hw);
    const unsigned int xlo = (unsigned int)xa;
    const unsigned int xhi = (unsigned int)(xa >> 32);

    const int k0 = (wv >> 1) << 8;           // 0 or 256 (wave-uniform)
    const unsigned long long ra =
        (unsigned long long)(const void*)cbp + (unsigned long long)k0 * (RS * 4);
    const unsigned int clo = __builtin_amdgcn_readfirstlane((unsigned int)ra);
    const unsigned int chi = __builtin_amdgcn_readfirstlane((unsigned int)(ra >> 32));
    const int k0s = __builtin_amdgcn_readfirstlane(k0);

    float m = 3.0e38f;
    int best = 0;

    asm volatile(
      // ---- prologue: x -> v16..v79 (coalesced, strided 16 KB).
      "v_mov_b32 v8, %[xlo]\n\t"
      "v_mov_b32 v9, %[xhi]\n\t"
      XLD("v16") XLD("v17") XLD("v18") XLD("v19")
      XLD("v20") XLD("v21") XLD("v22") XLD("v23")
      XLD("v24") XLD("v25") XLD("v26") XLD("v27")
      XLD("v28") XLD("v29") XLD("v30") XLD("v31")
      XLD("v32") XLD("v33") XLD("v34") XLD("v35")
      XLD("v36") XLD("v37") XLD("v38") XLD("v39")
      XLD("v40") XLD("v41") XLD("v42") XLD("v43")
      XLD("v44") XLD("v45") XLD("v46") XLD("v47")
      XLD("v48") XLD("v49") XLD("v50") XLD("v51")
      XLD("v52") XLD("v53") XLD("v54") XLD("v55")
      XLD("v56") XLD("v57") XLD("v58") XLD("v59")
      XLD("v60") XLD("v61") XLD("v62") XLD("v63")
      XLD("v64") XLD("v65") XLD("v66") XLD("v67")
      XLD("v68") XLD("v69") XLD("v70") XLD("v71")
      XLD("v72") XLD("v73") XLD("v74") XLD("v75")
      XLD("v76") XLD("v77") XLD("v78") XLD("v79")
      "s_waitcnt vmcnt(0)\n\t"
      // ---- Sx: rr[j]=x[j]^2 (j=0..7) then += x[8i+j]^2 ascending i; tree.
      "v_mul_f32 v80, v16, v16\n\t"  "v_mul_f32 v81, v17, v17\n\t"
      "v_mul_f32 v82, v18, v18\n\t"  "v_mul_f32 v83, v19, v19\n\t"
      "v_mul_f32 v84, v20, v20\n\t"  "v_mul_f32 v85, v21, v21\n\t"
      "v_mul_f32 v86, v22, v22\n\t"  "v_mul_f32 v87, v23, v23\n\t"
      "v_fmac_f32 v80, v24, v24\n\t" "v_fmac_f32 v81, v25, v25\n\t"
      "v_fmac_f32 v82, v26, v26\n\t" "v_fmac_f32 v83, v27, v27\n\t"
      "v_fmac_f32 v84, v28, v28\n\t" "v_fmac_f32 v85, v29, v29\n\t"
      "v_fmac_f32 v86, v30, v30\n\t" "v_fmac_f32 v87, v31, v31\n\t"
      "v_fmac_f32 v80, v32, v32\n\t" "v_fmac_f32 v81, v33, v33\n\t"
      "v_fmac_f32 v82, v34, v34\n\t" "v_fmac_f32 v83, v35, v35\n\t"
      "v_fmac_f32 v84, v36, v36\n\t" "v_fmac_f32 v85, v37, v37\n\t"
      "v_fmac_f32 v86, v38, v38\n\t" "v_fmac_f32 v87, v39, v39\n\t"
      "v_fmac_f32 v80, v40, v40\n\t" "v_fmac_f32 v81, v41, v41\n\t"
      "v_fmac_f32 v82, v42, v42\n\t" "v_fmac_f32 v83, v43, v43\n\t"
      "v_fmac_f32 v84, v44, v44\n\t" "v_fmac_f32 v85, v45, v45\n\t"
      "v_fmac_f32 v86, v46, v46\n\t" "v_fmac_f32 v87, v47, v47\n\t"
      "v_fmac_f32 v80, v48, v48\n\t" "v_fmac_f32 v81, v49, v49\n\t"
      "v_fmac_f32 v82, v50, v50\n\t" "v_fmac_f32 v83, v51, v51\n\t"
      "v_fmac_f32 v84, v52, v52\n\t" "v_fmac_f32 v85, v53, v53\n\t"
      "v_fmac_f32 v86, v54, v54\n\t" "v_fmac_f32 v87, v55, v55\n\t"
      "v_fmac_f32 v80, v56, v56\n\t" "v_fmac_f32 v81, v57, v57\n\t"
      "v_fmac_f32 v82, v58, v58\n\t" "v_fmac_f32 v83, v59, v59\n\t"
      "v_fmac_f32 v84, v60, v60\n\t" "v_fmac_f32 v85, v61, v61\n\t"
      "v_fmac_f32 v86, v62, v62\n\t" "v_fmac_f32 v87, v63, v63\n\t"
      "v_fmac_f32 v80, v64, v64\n\t" "v_fmac_f32 v81, v65, v65\n\t"
      "v_fmac_f32 v82, v66, v66\n\t" "v_fmac_f32 v83, v67, v67\n\t"
      "v_fmac_f32 v84, v68, v68\n\t" "v_fmac_f32 v85, v69, v69\n\t"
      "v_fmac_f32 v86, v70, v70\n\t" "v_fmac_f32 v87, v71, v71\n\t"
      "v_fmac_f32 v80, v72, v72\n\t" "v_fmac_f32 v81, v73, v73\n\t"
      "v_fmac_f32 v82, v74, v74\n\t" "v_fmac_f32 v83, v75, v75\n\t"
      "v_fmac_f32 v84, v76, v76\n\t" "v_fmac_f32 v85, v77, v77\n\t"
      "v_fmac_f32 v86, v78, v78\n\t" "v_fmac_f32 v87, v79, v79\n\t"
      "v_add_f32 v80, v80, v81\n\t"
      "v_add_f32 v82, v82, v83\n\t"
      "v_add_f32 v84, v84, v85\n\t"
      "v_add_f32 v86, v86, v87\n\t"
      "v_add_f32 v80, v80, v82\n\t"
      "v_add_f32 v84, v84, v86\n\t"
      "v_add_f32 v15, v80, v84\n\t"
      // ---- re-point to codebook; prime 13 loads: D0->P, D1->Q, sc0, D2->R.
      "v_mov_b32 v8, %[clo]\n\t"
      "v_mov_b32 v9, %[chi]\n\t"
      "v_mov_b32 v7, %[k0]\n\t"
      "s_mov_b32 s29, 85\n\t"
      LDP("0","16","32","48")
      LDQQ("64","80","96","112")
      LSC("v10","256")
      LDR("128","144","160","176")
      // ---- body: 3 codes per iteration, 85 iterations (codes 0..254).
      "Lvq%=:\n\t"
      // c0
      "s_waitcnt vmcnt(9)\n\t" FQ16(FM1, REGS_P, REGS_X0) LDP("192","208","224","240")
      "s_waitcnt vmcnt(9)\n\t" FQ16(F1,  REGS_Q, REGS_X1) LDQQ("272","288","304","320")
      "s_waitcnt vmcnt(8)\n\t" FQ16(F1,  REGS_R, REGS_X2) LDR("336","352","368","384") LSC("v11","528")
      "s_waitcnt vmcnt(9)\n\t" FQ16(F1,  REGS_P, REGS_X3) LDP("400","416","432","448")
      CMB("v10")
      // c1
      "s_waitcnt vmcnt(9)\n\t" FQ16(FM1, REGS_Q, REGS_X0) LDQQ("464","480","496","512")
      "s_waitcnt vmcnt(9)\n\t" FQ16(F1,  REGS_R, REGS_X1) LDR("544","560","576","592")
      "s_waitcnt vmcnt(8)\n\t" FQ16(F1,  REGS_P, REGS_X2) LDP("608","624","640","656") LSC("v12","800")
      "s_waitcnt vmcnt(9)\n\t" FQ16(F1,  REGS_Q, REGS_X3) LDQQ("672","688","704","720")
      CMB("v11")
      // c2
      "s_waitcnt vmcnt(9)\n\t" FQ16(FM1, REGS_R, REGS_X0) LDR("736","752","768","784")
      "s_waitcnt vmcnt(9)\n\t" FQ16(F1,  REGS_P, REGS_X1) LDP("816","832","848","864")
      "s_waitcnt vmcnt(8)\n\t" FQ16(F1,  REGS_Q, REGS_X2) LDQQ("880","896","912","928") LSC("v10","1072")
      "s_waitcnt vmcnt(9)\n\t" FQ16(F1,  REGS_R, REGS_X3) LDR("944","960","976","992")
      CMB("v12")
      // advance base by 3 rows (816 B) and loop.
      "v_add_co_u32 v8, vcc, 0x330, v8\n\t"
      "v_addc_co_u32 v9, vcc, 0, v9, vcc\n\t"
      "s_sub_u32 s29, s29, 1\n\t"
      "s_cmp_lg_u32 s29, 0\n\t"
      "s_cbranch_scc1 Lvq%=\n\t"
      // ---- tail: code 255 (outstanding: D1020,D1021,sc,D1022 = 13).
      "s_waitcnt vmcnt(9)\n\t" FQ16(FM1, REGS_P, REGS_X0) LDP("192","208","224","240")
      "s_waitcnt vmcnt(9)\n\t" FQ16(F1,  REGS_Q, REGS_X1)
      "s_waitcnt vmcnt(4)\n\t" FQ16(F1,  REGS_R, REGS_X2)
      "s_waitcnt vmcnt(0)\n\t" FQ16(F1,  REGS_P, REGS_X3)
      CMB("v10")
      : [mm] "+v"(m), [bb] "+v"(best)
      : [xlo] "v"(xlo), [xhi] "v"(xhi), [clo] "v"(clo), [chi] "v"(chi),
        [k0] "s"(k0s)
      : "vcc", "scc", "s29",
        "v7","v8","v9","v10","v11","v12","v13","v14","v15",
        "v16","v17","v18","v19","v20","v21","v22","v23",
        "v24","v25","v26","v27","v28","v29","v30","v31",
        "v32","v33","v34","v35","v36","v37","v38","v39",
        "v40","v41","v42","v43","v44","v45","v46","v47",
        "v48","v49","v50","v51","v52","v53","v54","v55",
        "v56","v57","v58","v59","v60","v61","v62","v63",
        "v64","v65","v66","v67","v68","v69","v70","v71",
        "v72","v73","v74","v75","v76","v77","v78","v79",
        "v80","v81","v82","v83","v84","v85","v86","v87",
        "v88","v89","v90","v91","v92","v93","v94","v95",
        "v96","v97","v98","v99","v100","v101","v102","v103",
        "v104","v105","v106","v107","v108","v109","v110","v111",
        "v112","v113","v114","v115","v116","v117","v118","v119",
        "v120","v121","v122","v123","v124","v125","v126","v127");

    // ---- Cross-half argmin: high half publishes; low half combines with
    // strict '<' (tie keeps low half's lower index = np.argmin).
    if (wv >= 2) { him[pxl] = m; hii[pxl] = best; }
    __syncthreads();

    float lossp = 0.f;
    if (wv < 2) {
      const float mh = him[pxl];
      const int ih = hii[pxl];
      if (mh < m) { m = mh; best = ih; }
      idx_out[px] = (float)best;
      const float* qrow = cb + (size_t)best * ND;
      float* op = out + (size_t)b * (ND * NHW) + hw;
#pragma unroll
      for (int dq = 0; dq < 16; ++dq) {
        const f4 qv = *(const f4*)(qrow + dq * 4);
        op[(size_t)(dq * 4 + 0) * NHW] = qv[0];
        op[(size_t)(dq * 4 + 1) * NHW] = qv[1];
        op[(size_t)(dq * 4 + 2) * NHW] = qv[2];
        op[(size_t)(dq * 4 + 3) * NHW] = qv[3];
      }
      lossp = m;   // min d2 == ||x - q||^2 (within ~1e-5 rounding)
    }
#pragma unroll
    for (int off = 32; off; off >>= 1) lossp += __shfl_down(lossp, off);
    if (lane == 0 && wv < 2) red[wv] = lossp;
    __syncthreads();
    if (tid == 0) {
      float t = (red[0] + red[1]) * (1.f / 8388608.f);
      atomicAdd(losses + 0, t);   // dictionary_loss
      atomicAdd(losses + 1, t);   // commitment_loss (identical forward value)
    }
  }
}

extern "C" void kernel_launch(void* const* d_in, const int* in_sizes, int n_in,
                              void* d_out, int out_size, void* d_ws, size_t ws_size,
                              hipStream_t stream) {
  const float* x  = (const float*)d_in[0];   // [32,64,64,64] fp32
  const float* cb = (const float*)d_in[1];   // [512,64] fp32
  float* out     = (float*)d_out;            // quantized [B,D,H,W]
  float* idx_out = out + OUT_ELEMS;          // indices (as fp32) [B,H,W]
  float* losses  = idx_out + NPIX;           // 2 scalars
  (void)d_ws; (void)ws_size;                 // packed codebook lives in a module global

  vq_prep<<<2, 256, 0, stream>>>(cb, losses);
  vq_main<<<NPIX / 128, 256, 0, stream>>>(x, cb, out, idx_out, losses);
}

// Round 9
// 224.178 us; speedup vs baseline: 2.4423x; 2.4423x over previous
//
#include <hip/hip_runtime.h>

#define NK 512
#define ND 64
#define NHW 4096
#define NPIX 131072            // 32*64*64
#define OUT_ELEMS 8388608      // 32*64*64*64
#define RS 80                  // packed codebook row stride (floats): 64 data + sc + 15 pad

typedef float f4 __attribute__((ext_vector_type(4)));

// Packed codebook: row k = {cb[k][0..63], sc[k], 15 pad}; 513 rows (row 512 is
// a phantom target for the final prefetch, never consumed). Rewritten by
// vq_prep every launch (stream-ordered before vq_main).
__device__ __attribute__((aligned(64))) float cbp[513 * RS];

// ---------------------------------------------------------------------------
// Prep: pack codebook + sc (numpy-pairwise-8 fp32 sum of fl(c_d^2)); zero the
// two loss slots (harness re-poisons d_out/d_ws to 0xAA every replay).
// ---------------------------------------------------------------------------
__global__ __launch_bounds__(256) void vq_prep(const float* __restrict__ cb,
                                               float* __restrict__ losses) {
#pragma clang fp contract(off)
  {
    const int k = blockIdx.x * 256 + threadIdx.x;   // grid 2*256 = 512
    const float* c = cb + (size_t)k * ND;
    float* dst = cbp + (size_t)k * RS;

    f4 v[16];
#pragma unroll
    for (int dq = 0; dq < 16; ++dq) {
      v[dq] = *(const f4*)(c + dq * 4);
      *(f4*)(dst + dq * 4) = v[dq];
    }
    float rr[8];
    rr[0] = v[0][0] * v[0][0]; rr[1] = v[0][1] * v[0][1];
    rr[2] = v[0][2] * v[0][2]; rr[3] = v[0][3] * v[0][3];
    rr[4] = v[1][0] * v[1][0]; rr[5] = v[1][1] * v[1][1];
    rr[6] = v[1][2] * v[1][2]; rr[7] = v[1][3] * v[1][3];
#pragma unroll
    for (int i = 2; i < 16; i += 2) {
      rr[0] += v[i][0] * v[i][0];     rr[1] += v[i][1] * v[i][1];
      rr[2] += v[i][2] * v[i][2];     rr[3] += v[i][3] * v[i][3];
      rr[4] += v[i + 1][0] * v[i + 1][0]; rr[5] += v[i + 1][1] * v[i + 1][1];
      rr[6] += v[i + 1][2] * v[i + 1][2]; rr[7] += v[i + 1][3] * v[i + 1][3];
    }
    dst[64] = ((rr[0] + rr[1]) + (rr[2] + rr[3])) + ((rr[4] + rr[5]) + (rr[6] + rr[7]));
    if (k < 2) losses[k] = 0.f;
  }
}

// ---- asm building blocks -------------------------------------------------
// Dual x load: pixel p (offset 0) and pixel p+64 (offset 256 B), then bump
// the strided address by 16 KB (one dim).
#define XLD2(V0, V1)                                             \
  "global_load_dword v" #V0 ", v[8:9], off\n\t"                  \
  "global_load_dword v" #V1 ", v[8:9], off offset:256\n\t"       \
  "v_add_co_u32 v8, vcc, 0x4000, v8\n\t"                         \
  "v_addc_co_u32 v9, vcc, 0, v9, vcc\n\t"
// Dual FMA: one codebook SGPR feeds both pixels' accumulators (v13 = acc0,
// v14 = acc1). Interleaving the two chains removes the 4-cyc fmac dep bubble.
#define FMP(S, X0, X1)                                           \
  "v_fmac_f32 v13, " S ", v" #X0 "\n\t"                          \
  "v_fmac_f32 v14, " S ", v" #X1 "\n\t"
#define FMP0(S, X0, X1)                                          \
  "v_mul_f32 v13, " S ", v" #X0 "\n\t"                           \
  "v_mul_f32 v14, " S ", v" #X1 "\n\t"
#define SXB(R, V) "v_mul_f32 v" #R ", v" #V ", v" #V "\n\t"
#define SXF(R, V) "v_fmac_f32 v" #R ", v" #V ", v" #V "\n\t"

// ---------------------------------------------------------------------------
// Main: lane = 2 pixels. Delivery-mechanism ranking measured so far:
// SMEM asm (R6: 162us) < LDS-tiled compiler (R1: 170) << VMEM-uniform
// (R8: 497 -- ~1150 cyc exposed per vmcnt wait; uniform VMEM latency is
// unhideable at this depth). R9 keeps R6's SMEM stream and attacks its
// ~700-cyc/drain cost from both sides: 2 px/lane halves codebook loads
// per CU (8 waves instead of 16 stream the same 4 s_load_x16/code) AND
// doubles each drain's FMA cover (64 insts), AND the interleaved acc0/acc1
// chains run at full issue rate (R6's single chain was 50% duty solo).
// Regs: v7 code ctr | v8:9 x addr | v10 Sx1 | v11/v12 d2 | v13/v14 acc |
// v15 Sx0 | v16-79 x0 | v80-87 rr scratch | v128-191 x1 |
// s28 sc | s29 ctr | s30:31 row addr | s36-67 A | s68-99 B.
// Geometry: 512 blocks x 256 thr; waves {0,1} px[0:128) K {0-255|256-511},
// waves {2,3} px[128:256); 2 blocks/CU = 2 waves/SIMD (VGPR budget 256).
// Numerics bit-identical per pixel to R6 (passed): v_mul + 63 v_fmac
// ascending d; d2 = fl(fl(Sx-2a)+sc) (fma with -2.0, 2a exact); Sx/sc
// pairwise-8; ascending codes, keep-old on >= (strict-< winner); cross-half
// tie keeps low half = np.argmin. Loss = m (min d2 == ||x-q||^2).
// ---------------------------------------------------------------------------
__global__ __launch_bounds__(256, 2) void vq_main(const float* __restrict__ x,
                                                  const float* __restrict__ cb,
                                                  float* __restrict__ out,
                                                  float* __restrict__ idx_out,
                                                  float* __restrict__ losses) {
#pragma clang fp contract(off)
  {
    __shared__ float him[256];
    __shared__ int   hii[256];
    __shared__ float red[4];

    const int tid = threadIdx.x;
    const int wv = tid >> 6;                 // 0..3
    const int lane = tid & 63;
    const int khalf = wv & 1;                // 0: codes 0-255, 1: 256-511
    const int p0 = ((wv >> 1) << 7) | lane;  // local pixel (0..127 or 128..255)
    const int p1 = p0 + 64;
    const int g0 = blockIdx.x * 256;
    const int b = g0 >> 12;                  // 256 | 4096 -> whole block same b
    const int hw0 = (g0 & 4095) + p0;

    const unsigned long long xa =
        (unsigned long long)(const void*)(x + (size_t)b * (ND * NHW) + hw0);
    const unsigned int xlo = (unsigned int)xa;
    const unsigned int xhi = (unsigned int)(xa >> 32);

    const int k0 = khalf << 8;               // wave-uniform
    const unsigned long long ra =
        (unsigned long long)(const void*)cbp + (unsigned long long)k0 * (RS * 4);
    const unsigned int rlo = __builtin_amdgcn_readfirstlane((unsigned int)ra);
    const unsigned int rhi = __builtin_amdgcn_readfirstlane((unsigned int)(ra >> 32));
    const unsigned long long rowa = ((unsigned long long)rhi << 32) | rlo;
    const int k0s = __builtin_amdgcn_readfirstlane(k0);

    float m0 = 3.0e38f, m1 = 3.0e38f;
    int b0 = 0, b1 = 0;

    asm volatile(
      // ---- prologue: x0 -> v16-79, x1 -> v128-191 (coalesced, 16KB stride).
      "v_mov_b32 v8, %[xlo]\n\t"
      "v_mov_b32 v9, %[xhi]\n\t"
      XLD2(16,128) XLD2(17,129) XLD2(18,130) XLD2(19,131)
      XLD2(20,132) XLD2(21,133) XLD2(22,134) XLD2(23,135)
      XLD2(24,136) XLD2(25,137) XLD2(26,138) XLD2(27,139)
      XLD2(28,140) XLD2(29,141) XLD2(30,142) XLD2(31,143)
      XLD2(32,144) XLD2(33,145) XLD2(34,146) XLD2(35,147)
      XLD2(36,148) XLD2(37,149) XLD2(38,150) XLD2(39,151)
      XLD2(40,152) XLD2(41,153) XLD2(42,154) XLD2(43,155)
      XLD2(44,156) XLD2(45,157) XLD2(46,158) XLD2(47,159)
      XLD2(48,160) XLD2(49,161) XLD2(50,162) XLD2(51,163)
      XLD2(52,164) XLD2(53,165) XLD2(54,166) XLD2(55,167)
      XLD2(56,168) XLD2(57,169) XLD2(58,170) XLD2(59,171)
      XLD2(60,172) XLD2(61,173) XLD2(62,174) XLD2(63,175)
      XLD2(64,176) XLD2(65,177) XLD2(66,178) XLD2(67,179)
      XLD2(68,180) XLD2(69,181) XLD2(70,182) XLD2(71,183)
      XLD2(72,184) XLD2(73,185) XLD2(74,186) XLD2(75,187)
      XLD2(76,188) XLD2(77,189) XLD2(78,190) XLD2(79,191)
      // issue A (code k0 dims 0-31) early: SMEM latency overlaps Sx compute.
      "s_mov_b64 s[30:31], %[rw]\n\t"
      "s_load_dwordx16 s[36:51], s[30:31], 0x0\n\t"
      "s_load_dwordx16 s[52:67], s[30:31], 0x40\n\t"
      "s_waitcnt vmcnt(0)\n\t"
      // ---- Sx0 (pairwise-8 of rounded squares) -> v15.
      SXB(80,16) SXB(81,17) SXB(82,18) SXB(83,19)
      SXB(84,20) SXB(85,21) SXB(86,22) SXB(87,23)
      SXF(80,24) SXF(81,25) SXF(82,26) SXF(83,27)
      SXF(84,28) SXF(85,29) SXF(86,30) SXF(87,31)
      SXF(80,32) SXF(81,33) SXF(82,34) SXF(83,35)
      SXF(84,36) SXF(85,37) SXF(86,38) SXF(87,39)
      SXF(80,40) SXF(81,41) SXF(82,42) SXF(83,43)
      SXF(84,44) SXF(85,45) SXF(86,46) SXF(87,47)
      SXF(80,48) SXF(81,49) SXF(82,50) SXF(83,51)
      SXF(84,52) SXF(85,53) SXF(86,54) SXF(87,55)
      SXF(80,56) SXF(81,57) SXF(82,58) SXF(83,59)
      SXF(84,60) SXF(85,61) SXF(86,62) SXF(87,63)
      SXF(80,64) SXF(81,65) SXF(82,66) SXF(83,67)
      SXF(84,68) SXF(85,69) SXF(86,70) SXF(87,71)
      SXF(80,72) SXF(81,73) SXF(82,74) SXF(83,75)
      SXF(84,76) SXF(85,77) SXF(86,78) SXF(87,79)
      "v_add_f32 v80, v80, v81\n\t"
      "v_add_f32 v82, v82, v83\n\t"
      "v_add_f32 v84, v84, v85\n\t"
      "v_add_f32 v86, v86, v87\n\t"
      "v_add_f32 v80, v80, v82\n\t"
      "v_add_f32 v84, v84, v86\n\t"
      "v_add_f32 v15, v80, v84\n\t"
      // ---- Sx1 -> v10.
      SXB(80,128) SXB(81,129) SXB(82,130) SXB(83,131)
      SXB(84,132) SXB(85,133) SXB(86,134) SXB(87,135)
      SXF(80,136) SXF(81,137) SXF(82,138) SXF(83,139)
      SXF(84,140) SXF(85,141) SXF(86,142) SXF(87,143)
      SXF(80,144) SXF(81,145) SXF(82,146) SXF(83,147)
      SXF(84,148) SXF(85,149) SXF(86,150) SXF(87,151)
      SXF(80,152) SXF(81,153) SXF(82,154) SXF(83,155)
      SXF(84,156) SXF(85,157) SXF(86,158) SXF(87,159)
      SXF(80,160) SXF(81,161) SXF(82,162) SXF(83,163)
      SXF(84,164) SXF(85,165) SXF(86,166) SXF(87,167)
      SXF(80,168) SXF(81,169) SXF(82,170) SXF(83,171)
      SXF(84,172) SXF(85,173) SXF(86,174) SXF(87,175)
      SXF(80,176) SXF(81,177) SXF(82,178) SXF(83,179)
      SXF(84,180) SXF(85,181) SXF(86,182) SXF(87,183)
      SXF(80,184) SXF(81,185) SXF(82,186) SXF(83,187)
      SXF(84,188) SXF(85,189) SXF(86,190) SXF(87,191)
      "v_add_f32 v80, v80, v81\n\t"
      "v_add_f32 v82, v82, v83\n\t"
      "v_add_f32 v84, v84, v85\n\t"
      "v_add_f32 v86, v86, v87\n\t"
      "v_add_f32 v80, v80, v82\n\t"
      "v_add_f32 v84, v84, v86\n\t"
      "v_add_f32 v10, v80, v84\n\t"
      "v_mov_b32 v7, %[k0]\n\t"
      "s_mov_b32 s29, 0x100\n\t"
      "s_waitcnt lgkmcnt(0)\n\t"
      // ---- K loop: 256 codes, one code per iteration.
      "Lvq%=:\n\t"
      // issue B (dims 32-63 of this code) + sc.
      "s_load_dwordx16 s[68:83], s[30:31], 0x80\n\t"
      "s_load_dwordx16 s[84:99], s[30:31], 0xc0\n\t"
      "s_load_dword s28, s[30:31], 0x100\n\t"
      // 64 FMAs on A (dims 0-31, both pixels).
      FMP0("s36",16,128) FMP("s37",17,129) FMP("s38",18,130) FMP("s39",19,131)
      FMP("s40",20,132)  FMP("s41",21,133) FMP("s42",22,134) FMP("s43",23,135)
      FMP("s44",24,136)  FMP("s45",25,137) FMP("s46",26,138) FMP("s47",27,139)
      FMP("s48",28,140)  FMP("s49",29,141) FMP("s50",30,142) FMP("s51",31,143)
      FMP("s52",32,144)  FMP("s53",33,145) FMP("s54",34,146) FMP("s55",35,147)
      FMP("s56",36,148)  FMP("s57",37,149) FMP("s58",38,150) FMP("s59",39,151)
      FMP("s60",40,152)  FMP("s61",41,153) FMP("s62",42,154) FMP("s63",43,155)
      FMP("s64",44,156)  FMP("s65",45,157) FMP("s66",46,158) FMP("s67",47,159)
      "s_waitcnt lgkmcnt(0)\n\t"
      // bump row, issue A' (next code dims 0-31; row 512 is the phantom).
      "s_add_u32 s30, s30, 0x140\n\t"
      "s_addc_u32 s31, s31, 0\n\t"
      "s_load_dwordx16 s[36:51], s[30:31], 0x0\n\t"
      "s_load_dwordx16 s[52:67], s[30:31], 0x40\n\t"
      // 64 FMAs on B (dims 32-63, both pixels).
      FMP("s68",48,160) FMP("s69",49,161) FMP("s70",50,162) FMP("s71",51,163)
      FMP("s72",52,164) FMP("s73",53,165) FMP("s74",54,166) FMP("s75",55,167)
      FMP("s76",56,168) FMP("s77",57,169) FMP("s78",58,170) FMP("s79",59,171)
      FMP("s80",60,172) FMP("s81",61,173) FMP("s82",62,174) FMP("s83",63,175)
      FMP("s84",64,176) FMP("s85",65,177) FMP("s86",66,178) FMP("s87",67,179)
      FMP("s88",68,180) FMP("s89",69,181) FMP("s90",70,182) FMP("s91",71,183)
      FMP("s92",72,184) FMP("s93",73,185) FMP("s94",74,186) FMP("s95",75,187)
      FMP("s96",76,188) FMP("s97",77,189) FMP("s98",78,190) FMP("s99",79,191)
      // combine + running argmin for both pixels (keep-old on >=).
      "v_fma_f32 v11, v13, -2.0, v15\n\t"
      "v_fma_f32 v12, v14, -2.0, v10\n\t"
      "v_add_f32 v11, s28, v11\n\t"
      "v_add_f32 v12, s28, v12\n\t"
      "v_cmp_ge_f32 vcc, v11, %[m0]\n\t"
      "v_cndmask_b32 %[b0], v7, %[b0], vcc\n\t"
      "v_cndmask_b32 %[m0], v11, %[m0], vcc\n\t"
      "v_cmp_ge_f32 vcc, v12, %[m1]\n\t"
      "v_cndmask_b32 %[b1], v7, %[b1], vcc\n\t"
      "v_cndmask_b32 %[m1], v12, %[m1], vcc\n\t"
      "v_add_u32 v7, 1, v7\n\t"
      "s_sub_u32 s29, s29, 1\n\t"
      "s_waitcnt lgkmcnt(0)\n\t"
      "s_cmp_lg_u32 s29, 0\n\t"
      "s_cbranch_scc1 Lvq%=\n\t"
      : [m0] "+v"(m0), [b0] "+v"(b0), [m1] "+v"(m1), [b1] "+v"(b1)
      : [xlo] "v"(xlo), [xhi] "v"(xhi), [rw] "s"(rowa), [k0] "s"(k0s)
      : "vcc", "scc",
        "s28","s29","s30","s31",
        "s36","s37","s38","s39","s40","s41","s42","s43",
        "s44","s45","s46","s47","s48","s49","s50","s51",
        "s52","s53","s54","s55","s56","s57","s58","s59",
        "s60","s61","s62","s63","s64","s65","s66","s67",
        "s68","s69","s70","s71","s72","s73","s74","s75",
        "s76","s77","s78","s79","s80","s81","s82","s83",
        "s84","s85","s86","s87","s88","s89","s90","s91",
        "s92","s93","s94","s95","s96","s97","s98","s99",
        "v7","v8","v9","v10","v11","v12","v13","v14","v15",
        "v16","v17","v18","v19","v20","v21","v22","v23",
        "v24","v25","v26","v27","v28","v29","v30","v31",
        "v32","v33","v34","v35","v36","v37","v38","v39",
        "v40","v41","v42","v43","v44","v45","v46","v47",
        "v48","v49","v50","v51","v52","v53","v54","v55",
        "v56","v57","v58","v59","v60","v61","v62","v63",
        "v64","v65","v66","v67","v68","v69","v70","v71",
        "v72","v73","v74","v75","v76","v77","v78","v79",
        "v80","v81","v82","v83","v84","v85","v86","v87",
        "v128","v129","v130","v131","v132","v133","v134","v135",
        "v136","v137","v138","v139","v140","v141","v142","v143",
        "v144","v145","v146","v147","v148","v149","v150","v151",
        "v152","v153","v154","v155","v156","v157","v158","v159",
        "v160","v161","v162","v163","v164","v165","v166","v167",
        "v168","v169","v170","v171","v172","v173","v174","v175",
        "v176","v177","v178","v179","v180","v181","v182","v183",
        "v184","v185","v186","v187","v188","v189","v190","v191");

    // ---- Cross-half argmin: high-K wave publishes; low-K wave combines
    // with strict '<' (tie keeps low half's lower index = np.argmin).
    if (khalf) {
      him[p0] = m0; hii[p0] = b0;
      him[p1] = m1; hii[p1] = b1;
    }
    __syncthreads();

    float lossp = 0.f;
    if (!khalf) {
      { const float mh = him[p0]; const int ih = hii[p0];
        if (mh < m0) { m0 = mh; b0 = ih; } }
      { const float mh = him[p1]; const int ih = hii[p1];
        if (mh < m1) { m1 = mh; b1 = ih; } }
      idx_out[g0 + p0] = (float)b0;
      idx_out[g0 + p1] = (float)b1;
      float* op = out + (size_t)b * (ND * NHW) + hw0;
      const float* q0 = cb + (size_t)b0 * ND;
      const float* q1 = cb + (size_t)b1 * ND;
#pragma unroll
      for (int dq = 0; dq < 16; ++dq) {
        const f4 qa = *(const f4*)(q0 + dq * 4);
        const f4 qb = *(const f4*)(q1 + dq * 4);
        op[(size_t)(dq * 4 + 0) * NHW] = qa[0];
        op[(size_t)(dq * 4 + 1) * NHW] = qa[1];
        op[(size_t)(dq * 4 + 2) * NHW] = qa[2];
        op[(size_t)(dq * 4 + 3) * NHW] = qa[3];
        op[(size_t)(dq * 4 + 0) * NHW + 64] = qb[0];
        op[(size_t)(dq * 4 + 1) * NHW + 64] = qb[1];
        op[(size_t)(dq * 4 + 2) * NHW + 64] = qb[2];
        op[(size_t)(dq * 4 + 3) * NHW + 64] = qb[3];
      }
      lossp = m0 + m1;   // min d2 == ||x - q||^2 (within ~1e-5 rounding)
    }
#pragma unroll
    for (int off = 32; off; off >>= 1) lossp += __shfl_down(lossp, off);
    if (lane == 0 && !khalf) red[wv] = lossp;
    __syncthreads();
    if (tid == 0) {
      float t = (red[0] + red[2]) * (1.f / 8388608.f);
      atomicAdd(losses + 0, t);   // dictionary_loss
      atomicAdd(losses + 1, t);   // commitment_loss (identical forward value)
    }
  }
}

extern "C" void kernel_launch(void* const* d_in, const int* in_sizes, int n_in,
                              void* d_out, int out_size, void* d_ws, size_t ws_size,
                              hipStream_t stream) {
  const float* x  = (const float*)d_in[0];   // [32,64,64,64] fp32
  const float* cb = (const float*)d_in[1];   // [512,64] fp32
  float* out     = (float*)d_out;            // quantized [B,D,H,W]
  float* idx_out = out + OUT_ELEMS;          // indices (as fp32) [B,H,W]
  float* losses  = idx_out + NPIX;           // 2 scalars
  (void)d_ws; (void)ws_size;                 // packed codebook lives in a module global

  vq_prep<<<2, 256, 0, stream>>>(cb, losses);
  vq_main<<<NPIX / 256, 256, 0, stream>>>(x, cb, out, idx_out, losses);
}

// Round 10
// 185.440 us; speedup vs baseline: 2.9524x; 1.2089x over previous
//
#include <hip/hip_runtime.h>

#define NK 512
#define ND 64
#define NHW 4096
#define NPIX 131072            // 32*64*64
#define OUT_ELEMS 8388608      // 32*64*64*64
#define RS 80                  // cbp row stride (floats); SMEM reads dims 0-31 only

typedef float f4 __attribute__((ext_vector_type(4)));

// cbp: row k = {cb[k][0..63], sc, pad} (513 rows; row 512 = phantom prefetch
// target). SMEM streams dims 0-31 from here.
__device__ __attribute__((aligned(64))) float cbp[513 * RS];
// cbp2: row k = {cb[k][32..63], sc[k], 3 pad} stride 36 floats (144 B).
// Staged into LDS once per block; ds_read-broadcast in the K loop.
__device__ __attribute__((aligned(64))) float cbp2[NK * 36];

// ---------------------------------------------------------------------------
// Prep: pack cbp + cbp2 (+ sc = numpy-pairwise-8 fp32 sum of fl(c_d^2));
// zero the loss slots (harness re-poisons d_out/d_ws every replay).
// ---------------------------------------------------------------------------
__global__ __launch_bounds__(256) void vq_prep(const float* __restrict__ cb,
                                               float* __restrict__ losses) {
#pragma clang fp contract(off)
  {
    const int k = blockIdx.x * 256 + threadIdx.x;   // grid 2*256 = 512
    const float* c = cb + (size_t)k * ND;
    float* dst = cbp + (size_t)k * RS;
    float* dst2 = cbp2 + (size_t)k * 36;

    f4 v[16];
#pragma unroll
    for (int dq = 0; dq < 16; ++dq) {
      v[dq] = *(const f4*)(c + dq * 4);
      *(f4*)(dst + dq * 4) = v[dq];
      if (dq >= 8) *(f4*)(dst2 + (dq - 8) * 4) = v[dq];   // dims 32..63
    }
    float rr[8];
    rr[0] = v[0][0] * v[0][0]; rr[1] = v[0][1] * v[0][1];
    rr[2] = v[0][2] * v[0][2]; rr[3] = v[0][3] * v[0][3];
    rr[4] = v[1][0] * v[1][0]; rr[5] = v[1][1] * v[1][1];
    rr[6] = v[1][2] * v[1][2]; rr[7] = v[1][3] * v[1][3];
#pragma unroll
    for (int i = 2; i < 16; i += 2) {
      rr[0] += v[i][0] * v[i][0];     rr[1] += v[i][1] * v[i][1];
      rr[2] += v[i][2] * v[i][2];     rr[3] += v[i][3] * v[i][3];
      rr[4] += v[i + 1][0] * v[i + 1][0]; rr[5] += v[i + 1][1] * v[i + 1][1];
      rr[6] += v[i + 1][2] * v[i + 1][2]; rr[7] += v[i + 1][3] * v[i + 1][3];
    }
    const float sc = ((rr[0] + rr[1]) + (rr[2] + rr[3])) + ((rr[4] + rr[5]) + (rr[6] + rr[7]));
    dst[64] = sc;
    dst2[32] = sc;
    dst2[33] = 0.f; dst2[34] = 0.f; dst2[35] = 0.f;
    if (k < 2) losses[k] = 0.f;
  }
}

// ---- asm building blocks -------------------------------------------------
#define XLD2(V0, V1)                                             \
  "global_load_dword v" #V0 ", v[8:9], off\n\t"                  \
  "global_load_dword v" #V1 ", v[8:9], off offset:256\n\t"       \
  "v_add_co_u32 v8, vcc, 0x4000, v8\n\t"                         \
  "v_addc_co_u32 v9, vcc, 0, v9, vcc\n\t"
#define FS(S, X0, X1)                                            \
  "v_fmac_f32 v13, " S ", v" #X0 "\n\t"                          \
  "v_fmac_f32 v14, " S ", v" #X1 "\n\t"
#define FS0(S, X0, X1)                                           \
  "v_mul_f32 v13, " S ", v" #X0 "\n\t"                           \
  "v_mul_f32 v14, " S ", v" #X1 "\n\t"
#define FV(C, X0, X1)                                            \
  "v_fmac_f32 v13, v" #C ", v" #X0 "\n\t"                        \
  "v_fmac_f32 v14, v" #C ", v" #X1 "\n\t"
#define SXB(R, V) "v_mul_f32 v" #R ", v" #V ", v" #V "\n\t"
#define SXF(R, V) "v_fmac_f32 v" #R ", v" #V ", v" #V "\n\t"
// combine: d2 = fma(a,-2,Sx)+sc; keep-old on >=, take-new on strict <.
#define CMB(SCV)                                                 \
  "v_fma_f32 v11, v13, -2.0, v15\n\t"                            \
  "v_fma_f32 v12, v14, -2.0, v10\n\t"                            \
  "v_add_f32 v11, " SCV ", v11\n\t"                              \
  "v_add_f32 v12, " SCV ", v12\n\t"                              \
  "v_cmp_ge_f32 vcc, v11, %[m0]\n\t"                             \
  "v_cndmask_b32 %[b0], v7, %[b0], vcc\n\t"                      \
  "v_cndmask_b32 %[m0], v11, %[m0], vcc\n\t"                     \
  "v_cmp_ge_f32 vcc, v12, %[m1]\n\t"                             \
  "v_cndmask_b32 %[b1], v7, %[b1], vcc\n\t"                      \
  "v_cndmask_b32 %[m1], v12, %[m1], vcc\n\t"                     \
  "v_add_u32 v7, 1, v7\n\t"

typedef const __attribute__((address_space(1))) unsigned int gu32;
typedef __attribute__((address_space(3))) unsigned int su32;

// ---------------------------------------------------------------------------
// Main: lane = 2 pixels (R9 geometry). R9 post-mortem: VALU busy 124us at
// ~4.2cyc/inst effective (m07: even pure-FMA ubench only hits 66% of the
// 2-cyc ideal), + ~37us of SMEM all-drain exposure; SMEM OOO returns cap the
// pipeline at 2 buffers, and cover x TLP is saturated (R6 == R9).
// R10 hybrid delivery, ONE all-drain per code with 128-FMA cover:
//   dims 0-31 via SMEM (2 s_load_dwordx16 -> 64 SGPR A/B rotate; half R9's
//     SQC pressure -> lower latency),
//   dims 32-63 + sc via LDS uniform ds_read broadcast (9 ops/code) from a
//     once-per-block staged copy (global_load_lds, hidden under x prologue).
// Both drain at a single lgkmcnt(0) placed 128 FMAs (~300-550cyc) after
// issue >= latency -> exposure ~0. LDS pipe worst case: 8 waves/CU x 256
// codes x 9 x 12cyc = 92us < VALU 124us. All-drain => OOO irrelevant.
// Regs: v6 lds addr | v7 code ctr | v8:9 addr | v10 Sx1 | v11/12 d2 |
// v13/14 acc | v15 Sx0 | v16-79 x0 | v80-143 x1 | v144-175 slot0 |
// v176-207 slot1 | v208/209 sc | s29 ctr | s30:31 row | s36-99 A/B.
// Geometry: 512 blocks x 256 thr; waves {0,1}: px 0-127, {2,3}: px 128-255;
// khalf = wv&1 (codes 0-255 | 256-511); 2 blocks/CU (LDS 76KB), 2 w/SIMD.
// Numerics bit-identical to R9 (passed): sequential fp32 FMA d=0..63 (SGPR
// then VGPR operands - rounding unchanged); d2 = fma(a,-2,Sx)+sc; Sx/sc
// pairwise-8; ascending codes, keep-old on >=; cross-half tie keeps low
// half = np.argmin. Loss = m.
// ---------------------------------------------------------------------------
__global__ __launch_bounds__(256, 2) void vq_main(const float* __restrict__ x,
                                                  const float* __restrict__ cb,
                                                  float* __restrict__ out,
                                                  float* __restrict__ idx_out,
                                                  float* __restrict__ losses) {
#pragma clang fp contract(off)
  {
    // Single LDS block => known offsets for asm ds_read (alloc starts at 0).
    // [0, 73728): staged cbp2 (512 x 144 B); [73728, 73872): phantom row;
    // [73872, 74896): him; [74896, 75920): hii; [75920, 75936): red.
    __shared__ __attribute__((aligned(16))) char smem[75936];
    float* him = (float*)(smem + 73872);
    int*   hii = (int*)(smem + 74896);
    float* red = (float*)(smem + 75920);

    const int tid = threadIdx.x;
    const int wv = tid >> 6;                 // 0..3
    const int lane = tid & 63;
    const int khalf = wv & 1;                // 0: codes 0-255, 1: 256-511
    const int p0 = ((wv >> 1) << 7) | lane;  // local pixel
    const int p1 = p0 + 64;
    const int g0 = blockIdx.x * 256;
    const int b = g0 >> 12;
    const int hw0 = (g0 & 4095) + p0;

    // ---- Stage cbp2 -> LDS (72 KB, 18 wave-chunks of 1 KB per wave).
#pragma unroll
    for (int i = 0; i < 18; ++i) {
      const int off = (wv + 4 * i) << 10;
      __builtin_amdgcn_global_load_lds(
          (gu32*)((const char*)cbp2 + off + lane * 16),
          (su32*)(smem + off), 16, 0, 0);
    }

    const unsigned long long xa =
        (unsigned long long)(const void*)(x + (size_t)b * (ND * NHW) + hw0);
    const unsigned int xlo = (unsigned int)xa;
    const unsigned int xhi = (unsigned int)(xa >> 32);

    const int k0 = khalf << 8;               // wave-uniform
    const unsigned long long ra =
        (unsigned long long)(const void*)cbp + (unsigned long long)k0 * (RS * 4);
    const unsigned int rlo = __builtin_amdgcn_readfirstlane((unsigned int)ra);
    const unsigned int rhi = __builtin_amdgcn_readfirstlane((unsigned int)(ra >> 32));
    const unsigned long long rowa = ((unsigned long long)rhi << 32) | rlo;
    const int k0s = __builtin_amdgcn_readfirstlane(k0);
    const unsigned int ldsoff = (unsigned int)khalf * 36864u;

    float m0 = 3.0e38f, m1 = 3.0e38f;
    int b0 = 0, b1 = 0;

    asm volatile(
      // ---- smem A <- code k0 dims 0-31 (latency overlaps x load + Sx).
      "s_mov_b64 s[30:31], %[rw]\n\t"
      "s_load_dwordx16 s[36:51], s[30:31], 0x0\n\t"
      "s_load_dwordx16 s[52:67], s[30:31], 0x40\n\t"
      // ---- x0 -> v16-79, x1 -> v80-143 (coalesced, 16 KB stride).
      "v_mov_b32 v8, %[xlo]\n\t"
      "v_mov_b32 v9, %[xhi]\n\t"
      XLD2(16,80)  XLD2(17,81)  XLD2(18,82)  XLD2(19,83)
      XLD2(20,84)  XLD2(21,85)  XLD2(22,86)  XLD2(23,87)
      XLD2(24,88)  XLD2(25,89)  XLD2(26,90)  XLD2(27,91)
      XLD2(28,92)  XLD2(29,93)  XLD2(30,94)  XLD2(31,95)
      XLD2(32,96)  XLD2(33,97)  XLD2(34,98)  XLD2(35,99)
      XLD2(36,100) XLD2(37,101) XLD2(38,102) XLD2(39,103)
      XLD2(40,104) XLD2(41,105) XLD2(42,106) XLD2(43,107)
      XLD2(44,108) XLD2(45,109) XLD2(46,110) XLD2(47,111)
      XLD2(48,112) XLD2(49,113) XLD2(50,114) XLD2(51,115)
      XLD2(52,116) XLD2(53,117) XLD2(54,118) XLD2(55,119)
      XLD2(56,120) XLD2(57,121) XLD2(58,122) XLD2(59,123)
      XLD2(60,124) XLD2(61,125) XLD2(62,126) XLD2(63,127)
      XLD2(64,128) XLD2(65,129) XLD2(66,130) XLD2(67,131)
      XLD2(68,132) XLD2(69,133) XLD2(70,134) XLD2(71,135)
      XLD2(72,136) XLD2(73,137) XLD2(74,138) XLD2(75,139)
      XLD2(76,140) XLD2(77,141) XLD2(78,142) XLD2(79,143)
      "s_waitcnt vmcnt(0)\n\t"               // x + this wave's staging done
      "s_barrier\n\t"                        // all waves' staging visible
      // ---- Sx0 -> v15 (pairwise-8 of rounded squares; scratch v144-151).
      SXB(144,16) SXB(145,17) SXB(146,18) SXB(147,19)
      SXB(148,20) SXB(149,21) SXB(150,22) SXB(151,23)
      SXF(144,24) SXF(145,25) SXF(146,26) SXF(147,27)
      SXF(148,28) SXF(149,29) SXF(150,30) SXF(151,31)
      SXF(144,32) SXF(145,33) SXF(146,34) SXF(147,35)
      SXF(148,36) SXF(149,37) SXF(150,38) SXF(151,39)
      SXF(144,40) SXF(145,41) SXF(146,42) SXF(147,43)
      SXF(148,44) SXF(149,45) SXF(150,46) SXF(151,47)
      SXF(144,48) SXF(145,49) SXF(146,50) SXF(147,51)
      SXF(148,52) SXF(149,53) SXF(150,54) SXF(151,55)
      SXF(144,56) SXF(145,57) SXF(146,58) SXF(147,59)
      SXF(148,60) SXF(149,61) SXF(150,62) SXF(151,63)
      SXF(144,64) SXF(145,65) SXF(146,66) SXF(147,67)
      SXF(148,68) SXF(149,69) SXF(150,70) SXF(151,71)
      SXF(144,72) SXF(145,73) SXF(146,74) SXF(147,75)
      SXF(148,76) SXF(149,77) SXF(150,78) SXF(151,79)
      "v_add_f32 v144, v144, v145\n\t"
      "v_add_f32 v146, v146, v147\n\t"
      "v_add_f32 v148, v148, v149\n\t"
      "v_add_f32 v150, v150, v151\n\t"
      "v_add_f32 v144, v144, v146\n\t"
      "v_add_f32 v148, v148, v150\n\t"
      "v_add_f32 v15, v144, v148\n\t"
      // ---- Sx1 -> v10.
      SXB(144,80)  SXB(145,81)  SXB(146,82)  SXB(147,83)
      SXB(148,84)  SXB(149,85)  SXB(150,86)  SXB(151,87)
      SXF(144,88)  SXF(145,89)  SXF(146,90)  SXF(147,91)
      SXF(148,92)  SXF(149,93)  SXF(150,94)  SXF(151,95)
      SXF(144,96)  SXF(145,97)  SXF(146,98)  SXF(147,99)
      SXF(148,100) SXF(149,101) SXF(150,102) SXF(151,103)
      SXF(144,104) SXF(145,105) SXF(146,106) SXF(147,107)
      SXF(148,108) SXF(149,109) SXF(150,110) SXF(151,111)
      SXF(144,112) SXF(145,113) SXF(146,114) SXF(147,115)
      SXF(148,116) SXF(149,117) SXF(150,118) SXF(151,119)
      SXF(144,120) SXF(145,121) SXF(146,122) SXF(147,123)
      SXF(148,124) SXF(149,125) SXF(150,126) SXF(151,127)
      SXF(144,128) SXF(145,129) SXF(146,130) SXF(147,131)
      SXF(148,132) SXF(149,133) SXF(150,134) SXF(151,135)
      SXF(144,136) SXF(145,137) SXF(146,138) SXF(147,139)
      SXF(148,140) SXF(149,141) SXF(150,142) SXF(151,143)
      "v_add_f32 v144, v144, v145\n\t"
      "v_add_f32 v146, v146, v147\n\t"
      "v_add_f32 v148, v148, v149\n\t"
      "v_add_f32 v150, v150, v151\n\t"
      "v_add_f32 v144, v144, v146\n\t"
      "v_add_f32 v148, v148, v150\n\t"
      "v_add_f32 v10, v144, v148\n\t"
      // ---- lds slot0 <- code k0 dims 32-63 + sc; counters.
      "v_mov_b32 v7, %[k0]\n\t"
      "v_mov_b32 v6, %[lo6]\n\t"
      "ds_read_b128 v[144:147], v6 offset:0\n\t"
      "ds_read_b128 v[148:151], v6 offset:16\n\t"
      "ds_read_b128 v[152:155], v6 offset:32\n\t"
      "ds_read_b128 v[156:159], v6 offset:48\n\t"
      "ds_read_b128 v[160:163], v6 offset:64\n\t"
      "ds_read_b128 v[164:167], v6 offset:80\n\t"
      "ds_read_b128 v[168:171], v6 offset:96\n\t"
      "ds_read_b128 v[172:175], v6 offset:112\n\t"
      "ds_read_b32  v208, v6 offset:128\n\t"
      "s_mov_b32 s29, 128\n\t"
      "s_waitcnt lgkmcnt(0)\n\t"
      // ================= K loop: 2 codes per iteration =================
      "Lvq%=:\n\t"
      // ---- code c (A/slot0); prefetch c+1 -> B/slot1.
      "s_add_u32 s30, s30, 0x140\n\t"
      "s_addc_u32 s31, s31, 0\n\t"
      "s_load_dwordx16 s[68:83], s[30:31], 0x0\n\t"
      "s_load_dwordx16 s[84:99], s[30:31], 0x40\n\t"
      "ds_read_b128 v[176:179], v6 offset:144\n\t"
      "ds_read_b128 v[180:183], v6 offset:160\n\t"
      "ds_read_b128 v[184:187], v6 offset:176\n\t"
      "ds_read_b128 v[188:191], v6 offset:192\n\t"
      "ds_read_b128 v[192:195], v6 offset:208\n\t"
      "ds_read_b128 v[196:199], v6 offset:224\n\t"
      "ds_read_b128 v[200:203], v6 offset:240\n\t"
      "ds_read_b128 v[204:207], v6 offset:256\n\t"
      "ds_read_b32  v209, v6 offset:272\n\t"
      FS0("s36",16,80) FS("s37",17,81)  FS("s38",18,82)  FS("s39",19,83)
      FS("s40",20,84)  FS("s41",21,85)  FS("s42",22,86)  FS("s43",23,87)
      FS("s44",24,88)  FS("s45",25,89)  FS("s46",26,90)  FS("s47",27,91)
      FS("s48",28,92)  FS("s49",29,93)  FS("s50",30,94)  FS("s51",31,95)
      FS("s52",32,96)  FS("s53",33,97)  FS("s54",34,98)  FS("s55",35,99)
      FS("s56",36,100) FS("s57",37,101) FS("s58",38,102) FS("s59",39,103)
      FS("s60",40,104) FS("s61",41,105) FS("s62",42,106) FS("s63",43,107)
      FS("s64",44,108) FS("s65",45,109) FS("s66",46,110) FS("s67",47,111)
      FV(144,48,112) FV(145,49,113) FV(146,50,114) FV(147,51,115)
      FV(148,52,116) FV(149,53,117) FV(150,54,118) FV(151,55,119)
      FV(152,56,120) FV(153,57,121) FV(154,58,122) FV(155,59,123)
      FV(156,60,124) FV(157,61,125) FV(158,62,126) FV(159,63,127)
      FV(160,64,128) FV(161,65,129) FV(162,66,130) FV(163,67,131)
      FV(164,68,132) FV(165,69,133) FV(166,70,134) FV(167,71,135)
      FV(168,72,136) FV(169,73,137) FV(170,74,138) FV(171,75,139)
      FV(172,76,140) FV(173,77,141) FV(174,78,142) FV(175,79,143)
      CMB("v208")
      "s_waitcnt lgkmcnt(0)\n\t"
      // ---- code c+1 (B/slot1); prefetch c+2 -> A/slot0.
      "s_add_u32 s30, s30, 0x140\n\t"
      "s_addc_u32 s31, s31, 0\n\t"
      "s_load_dwordx16 s[36:51], s[30:31], 0x0\n\t"
      "s_load_dwordx16 s[52:67], s[30:31], 0x40\n\t"
      "ds_read_b128 v[144:147], v6 offset:288\n\t"
      "ds_read_b128 v[148:151], v6 offset:304\n\t"
      "ds_read_b128 v[152:155], v6 offset:320\n\t"
      "ds_read_b128 v[156:159], v6 offset:336\n\t"
      "ds_read_b128 v[160:163], v6 offset:352\n\t"
      "ds_read_b128 v[164:167], v6 offset:368\n\t"
      "ds_read_b128 v[168:171], v6 offset:384\n\t"
      "ds_read_b128 v[172:175], v6 offset:400\n\t"
      "ds_read_b32  v208, v6 offset:416\n\t"
      FS0("s68",16,80) FS("s69",17,81)  FS("s70",18,82)  FS("s71",19,83)
      FS("s72",20,84)  FS("s73",21,85)  FS("s74",22,86)  FS("s75",23,87)
      FS("s76",24,88)  FS("s77",25,89)  FS("s78",26,90)  FS("s79",27,91)
      FS("s80",28,92)  FS("s81",29,93)  FS("s82",30,94)  FS("s83",31,95)
      FS("s84",32,96)  FS("s85",33,97)  FS("s86",34,98)  FS("s87",35,99)
      FS("s88",36,100) FS("s89",37,101) FS("s90",38,102) FS("s91",39,103)
      FS("s92",40,104) FS("s93",41,105) FS("s94",42,106) FS("s95",43,107)
      FS("s96",44,108) FS("s97",45,109) FS("s98",46,110) FS("s99",47,111)
      FV(176,48,112) FV(177,49,113) FV(178,50,114) FV(179,51,115)
      FV(180,52,116) FV(181,53,117) FV(182,54,118) FV(183,55,119)
      FV(184,56,120) FV(185,57,121) FV(186,58,122) FV(187,59,123)
      FV(188,60,124) FV(189,61,125) FV(190,62,126) FV(191,63,127)
      FV(192,64,128) FV(193,65,129) FV(194,66,130) FV(195,67,131)
      FV(196,68,132) FV(197,69,133) FV(198,70,134) FV(199,71,135)
      FV(200,72,136) FV(201,73,137) FV(202,74,138) FV(203,75,139)
      FV(204,76,140) FV(205,77,141) FV(206,78,142) FV(207,79,143)
      CMB("v209")
      "v_add_u32 v6, 0x120, v6\n\t"
      "s_sub_u32 s29, s29, 1\n\t"
      "s_waitcnt lgkmcnt(0)\n\t"
      "s_cmp_lg_u32 s29, 0\n\t"
      "s_cbranch_scc1 Lvq%=\n\t"
      : [m0] "+v"(m0), [b0] "+v"(b0), [m1] "+v"(m1), [b1] "+v"(b1)
      : [xlo] "v"(xlo), [xhi] "v"(xhi), [rw] "s"(rowa), [k0] "s"(k0s),
        [lo6] "v"(ldsoff)
      : "vcc", "scc",
        "s29","s30","s31",
        "s36","s37","s38","s39","s40","s41","s42","s43",
        "s44","s45","s46","s47","s48","s49","s50","s51",
        "s52","s53","s54","s55","s56","s57","s58","s59",
        "s60","s61","s62","s63","s64","s65","s66","s67",
        "s68","s69","s70","s71","s72","s73","s74","s75",
        "s76","s77","s78","s79","s80","s81","s82","s83",
        "s84","s85","s86","s87","s88","s89","s90","s91",
        "s92","s93","s94","s95","s96","s97","s98","s99",
        "v6","v7","v8","v9","v10","v11","v12","v13","v14","v15",
        "v16","v17","v18","v19","v20","v21","v22","v23",
        "v24","v25","v26","v27","v28","v29","v30","v31",
        "v32","v33","v34","v35","v36","v37","v38","v39",
        "v40","v41","v42","v43","v44","v45","v46","v47",
        "v48","v49","v50","v51","v52","v53","v54","v55",
        "v56","v57","v58","v59","v60","v61","v62","v63",
        "v64","v65","v66","v67","v68","v69","v70","v71",
        "v72","v73","v74","v75","v76","v77","v78","v79",
        "v80","v81","v82","v83","v84","v85","v86","v87",
        "v88","v89","v90","v91","v92","v93","v94","v95",
        "v96","v97","v98","v99","v100","v101","v102","v103",
        "v104","v105","v106","v107","v108","v109","v110","v111",
        "v112","v113","v114","v115","v116","v117","v118","v119",
        "v120","v121","v122","v123","v124","v125","v126","v127",
        "v128","v129","v130","v131","v132","v133","v134","v135",
        "v136","v137","v138","v139","v140","v141","v142","v143",
        "v144","v145","v146","v147","v148","v149","v150","v151",
        "v152","v153","v154","v155","v156","v157","v158","v159",
        "v160","v161","v162","v163","v164","v165","v166","v167",
        "v168","v169","v170","v171","v172","v173","v174","v175",
        "v176","v177","v178","v179","v180","v181","v182","v183",
        "v184","v185","v186","v187","v188","v189","v190","v191",
        "v192","v193","v194","v195","v196","v197","v198","v199",
        "v200","v201","v202","v203","v204","v205","v206","v207",
        "v208","v209");

    // ---- Cross-half argmin: high-K wave publishes; low-K wave combines
    // with strict '<' (tie keeps low half's lower index = np.argmin).
    if (khalf) {
      him[p0] = m0; hii[p0] = b0;
      him[p1] = m1; hii[p1] = b1;
    }
    __syncthreads();

    float lossp = 0.f;
    if (!khalf) {
      { const float mh = him[p0]; const int ih = hii[p0];
        if (mh < m0) { m0 = mh; b0 = ih; } }
      { const float mh = him[p1]; const int ih = hii[p1];
        if (mh < m1) { m1 = mh; b1 = ih; } }
      idx_out[g0 + p0] = (float)b0;
      idx_out[g0 + p1] = (float)b1;
      float* op = out + (size_t)b * (ND * NHW) + hw0;
      const float* q0 = cb + (size_t)b0 * ND;
      const float* q1 = cb + (size_t)b1 * ND;
#pragma unroll
      for (int dq = 0; dq < 16; ++dq) {
        const f4 qa = *(const f4*)(q0 + dq * 4);
        const f4 qb = *(const f4*)(q1 + dq * 4);
        op[(size_t)(dq * 4 + 0) * NHW] = qa[0];
        op[(size_t)(dq * 4 + 1) * NHW] = qa[1];
        op[(size_t)(dq * 4 + 2) * NHW] = qa[2];
        op[(size_t)(dq * 4 + 3) * NHW] = qa[3];
        op[(size_t)(dq * 4 + 0) * NHW + 64] = qb[0];
        op[(size_t)(dq * 4 + 1) * NHW + 64] = qb[1];
        op[(size_t)(dq * 4 + 2) * NHW + 64] = qb[2];
        op[(size_t)(dq * 4 + 3) * NHW + 64] = qb[3];
      }
      lossp = m0 + m1;   // min d2 == ||x - q||^2 (within ~1e-5 rounding)
    }
#pragma unroll
    for (int off = 32; off; off >>= 1) lossp += __shfl_down(lossp, off);
    if (lane == 0 && !khalf) red[wv] = lossp;
    __syncthreads();
    if (tid == 0) {
      float t = (red[0] + red[2]) * (1.f / 8388608.f);
      atomicAdd(losses + 0, t);   // dictionary_loss
      atomicAdd(losses + 1, t);   // commitment_loss (identical forward value)
    }
  }
}

extern "C" void kernel_launch(void* const* d_in, const int* in_sizes, int n_in,
                              void* d_out, int out_size, void* d_ws, size_t ws_size,
                              hipStream_t stream) {
  const float* x  = (const float*)d_in[0];   // [32,64,64,64] fp32
  const float* cb = (const float*)d_in[1];   // [512,64] fp32
  float* out     = (float*)d_out;            // quantized [B,D,H,W]
  float* idx_out = out + OUT_ELEMS;          // indices (as fp32) [B,H,W]
  float* losses  = idx_out + NPIX;           // 2 scalars
  (void)d_ws; (void)ws_size;                 // packed tables live in module globals

  vq_prep<<<2, 256, 0, stream>>>(cb, losses);
  vq_main<<<NPIX / 256, 256, 0, stream>>>(x, cb, out, idx_out, losses);
}

// Round 11
// 178.692 us; speedup vs baseline: 3.0639x; 1.0378x over previous
//
#include <hip/hip_runtime.h>

#define NK 512
#define ND 64
#define NHW 4096
#define NPIX 131072            // 32*64*64
#define OUT_ELEMS 8388608      // 32*64*64*64
#define RS 80                  // cbp row stride (floats): 64 data + sc + 15 pad

typedef float f4 __attribute__((ext_vector_type(4)));

// cbp: row k = {cb[k][0..63], sc, pad}, 513 rows (row 512 = phantom prefetch
// target). SMEM streams dims 0-31 + sc from here.
__device__ __attribute__((aligned(64))) float cbp[513 * RS];
// cbp2: row k = {cb[k][32..63]} stride 32 floats (128 B). Staged to LDS once
// per block; uniform ds_read_b128 in the K loop.
__device__ __attribute__((aligned(64))) float cbp2[NK * 32];

// ---------------------------------------------------------------------------
// Prep: pack cbp + cbp2 (+ sc = numpy-pairwise-8 fp32 sum of fl(c_d^2));
// zero the loss slots (harness re-poisons d_out/d_ws every replay).
// ---------------------------------------------------------------------------
__global__ __launch_bounds__(256) void vq_prep(const float* __restrict__ cb,
                                               float* __restrict__ losses) {
#pragma clang fp contract(off)
  {
    const int k = blockIdx.x * 256 + threadIdx.x;   // grid 2*256 = 512
    const float* c = cb + (size_t)k * ND;
    float* dst = cbp + (size_t)k * RS;
    float* dst2 = cbp2 + (size_t)k * 32;

    f4 v[16];
#pragma unroll
    for (int dq = 0; dq < 16; ++dq) {
      v[dq] = *(const f4*)(c + dq * 4);
      *(f4*)(dst + dq * 4) = v[dq];
      if (dq >= 8) *(f4*)(dst2 + (dq - 8) * 4) = v[dq];   // dims 32..63
    }
    float rr[8];
    rr[0] = v[0][0] * v[0][0]; rr[1] = v[0][1] * v[0][1];
    rr[2] = v[0][2] * v[0][2]; rr[3] = v[0][3] * v[0][3];
    rr[4] = v[1][0] * v[1][0]; rr[5] = v[1][1] * v[1][1];
    rr[6] = v[1][2] * v[1][2]; rr[7] = v[1][3] * v[1][3];
#pragma unroll
    for (int i = 2; i < 16; i += 2) {
      rr[0] += v[i][0] * v[i][0];     rr[1] += v[i][1] * v[i][1];
      rr[2] += v[i][2] * v[i][2];     rr[3] += v[i][3] * v[i][3];
      rr[4] += v[i + 1][0] * v[i + 1][0]; rr[5] += v[i + 1][1] * v[i + 1][1];
      rr[6] += v[i + 1][2] * v[i + 1][2]; rr[7] += v[i + 1][3] * v[i + 1][3];
    }
    dst[64] = ((rr[0] + rr[1]) + (rr[2] + rr[3])) + ((rr[4] + rr[5]) + (rr[6] + rr[7]));
    if (k < 2) losses[k] = 0.f;
  }
}

// ---- asm building blocks -------------------------------------------------
// x pair load: dim d of pixel0 -> even reg, pixel1 (px+64, +256 B) -> odd reg.
#define XLD2(V0, V1)                                             \
  "global_load_dword v" #V0 ", v[8:9], off\n\t"                  \
  "global_load_dword v" #V1 ", v[8:9], off offset:256\n\t"       \
  "v_add_co_u32 v8, vcc, 0x4000, v8\n\t"                         \
  "v_addc_co_u32 v9, vcc, 0, v9, vcc\n\t"
// Packed FMA: lo half = pixel0 chain, hi half = pixel1 chain; codebook value
// broadcast from the LO (even dim) or HI (odd dim) half of an aligned pair.
// Each pixel's d=0..63 sequential fp32 chain is preserved bit-identically.
#define PKE(CP, XP) "v_pk_fma_f32 v[12:13], " CP ", " XP ", v[12:13] op_sel:[0,0,0] op_sel_hi:[0,1,1]\n\t"
#define PKO(CP, XP) "v_pk_fma_f32 v[12:13], " CP ", " XP ", v[12:13] op_sel:[1,0,0] op_sel_hi:[1,1,1]\n\t"
#define PKP(CP, XE, XO)  PKE(CP, XE) PKO(CP, XO)
#define PKP0(CP, XE, XO)                                         \
  "v_pk_mul_f32 v[12:13], " CP ", " XE " op_sel:[0,0] op_sel_hi:[0,1]\n\t" \
  PKO(CP, XO)
// Sx: packed squares (lo=px0, hi=px1), per-half order = prior rounds.
#define SQ0(P, X) "v_pk_mul_f32 " P ", " X ", " X "\n\t"
#define SQA(P, X) "v_pk_fma_f32 " P ", " X ", " X ", " P "\n\t"
#define PADD(D, A, B) "v_pk_add_f32 " D ", " A ", " B "\n\t"
// combine: d2 = fma(acc,-2,Sx) + sc; keep-old on >=, take-new on strict <.
#define CMB(SCS)                                                 \
  "v_fma_f32 v8, v12, -2.0, v10\n\t"                             \
  "v_fma_f32 v9, v13, -2.0, v11\n\t"                             \
  "v_add_f32 v8, " SCS ", v8\n\t"                                \
  "v_add_f32 v9, " SCS ", v9\n\t"                                \
  "v_cmp_ge_f32 vcc, v8, %[m0]\n\t"                              \
  "v_cndmask_b32 %[b0], v7, %[b0], vcc\n\t"                      \
  "v_cndmask_b32 %[m0], v8, %[m0], vcc\n\t"                      \
  "v_cmp_ge_f32 vcc, v9, %[m1]\n\t"                              \
  "v_cndmask_b32 %[b1], v7, %[b1], vcc\n\t"                      \
  "v_cndmask_b32 %[m1], v9, %[m1], vcc\n\t"                      \
  "v_add_u32 v7, 1, v7\n\t"

typedef const __attribute__((address_space(1))) unsigned int gu32;
typedef __attribute__((address_space(3))) unsigned int su32;

// ---------------------------------------------------------------------------
// Main: lane = 2 pixels (R10 geometry + hybrid delivery). R10 accounting:
// 1163 cyc/code/SIMD = VALU 556 + LDS ~864/CU + SMEM residual -> three-way
// pipe saturation. R11 halves VALU instruction count via v_pk_fma_f32: the
// two PIXELS ride the packed halves (lo=px0, hi=px1), so each pixel's
// sequential d=0..63 fp32 chain is bit-identical to R10; codebook scalar is
// broadcast via op_sel half-selects (even dim -> lo of pair, odd -> hi).
// sc moves to SMEM (s_load_dword off the cbp row) -> LDS 9 -> 8 ops/code,
// staged table 72 -> 64 KB. FMAs/code: 64 pk (was 128 scalar) + CMB ~11.
// Regs: v6 lds addr | v7 code ctr | v8:9 x addr then d2 | v[10:11] Sx pair |
// v[12:13] acc pair | v16-143 x interleaved (dim d -> v[16+2d],v[17+2d]) |
// v144-175 slot0 | v176-207 slot1 | s28/s34 sc | s29 ctr | s30:31 row |
// s36-67 A | s68-99 B.
// Geometry: 512 blocks x 256 thr; waves {0,2}: khalf=0 (codes 0-255),
// {1,3}: khalf=1; wv>>1 selects pixel group; 2 blocks/CU, 2 waves/SIMD.
// Numerics bit-identical to R10 (passed): per-pixel sequential fp32 FMA
// chain d=0..63; d2 = fma(acc,-2,Sx)+sc; Sx/sc pairwise-8; ascending codes,
// keep-old on >=; cross-half tie keeps low half = np.argmin. Loss = m.
// ---------------------------------------------------------------------------
__global__ __launch_bounds__(256, 2) void vq_main(const float* __restrict__ x,
                                                  const float* __restrict__ cb,
                                                  float* __restrict__ out,
                                                  float* __restrict__ idx_out,
                                                  float* __restrict__ losses) {
#pragma clang fp contract(off)
  {
    // [0, 65536): staged cbp2 (512 x 128 B); [65536, 65664): phantom row;
    // [65664, 66688): him; [66688, 67712): hii; [67712, 67728): red.
    __shared__ __attribute__((aligned(16))) char smem[67728];
    float* him = (float*)(smem + 65664);
    int*   hii = (int*)(smem + 66688);
    float* red = (float*)(smem + 67712);

    const int tid = threadIdx.x;
    const int wv = tid >> 6;                 // 0..3
    const int lane = tid & 63;
    const int khalf = wv & 1;                // 0: codes 0-255, 1: 256-511
    const int p0 = ((wv >> 1) << 7) | lane;  // local pixel
    const int p1 = p0 + 64;
    const int g0 = blockIdx.x * 256;
    const int b = g0 >> 12;
    const int hw0 = (g0 & 4095) + p0;

    // ---- Stage cbp2 -> LDS (64 KB, 16 x 1 KB chunks per wave).
#pragma unroll
    for (int i = 0; i < 16; ++i) {
      const int off = (wv + 4 * i) << 10;
      __builtin_amdgcn_global_load_lds(
          (gu32*)((const char*)cbp2 + off + lane * 16),
          (su32*)(smem + off), 16, 0, 0);
    }

    const unsigned long long xa =
        (unsigned long long)(const void*)(x + (size_t)b * (ND * NHW) + hw0);
    const unsigned int xlo = (unsigned int)xa;
    const unsigned int xhi = (unsigned int)(xa >> 32);

    const int k0 = khalf << 8;               // wave-uniform
    const unsigned long long ra =
        (unsigned long long)(const void*)cbp + (unsigned long long)k0 * (RS * 4);
    const unsigned int rlo = __builtin_amdgcn_readfirstlane((unsigned int)ra);
    const unsigned int rhi = __builtin_amdgcn_readfirstlane((unsigned int)(ra >> 32));
    const unsigned long long rowa = ((unsigned long long)rhi << 32) | rlo;
    const int k0s = __builtin_amdgcn_readfirstlane(k0);
    const unsigned int ldsoff = (unsigned int)khalf * 32768u;

    float m0 = 3.0e38f, m1 = 3.0e38f;
    int b0 = 0, b1 = 0;

    asm volatile(
      // ---- smem A <- code k0 dims 0-31 + sc (overlaps x load + Sx).
      "s_mov_b64 s[30:31], %[rw]\n\t"
      "s_load_dwordx16 s[36:51], s[30:31], 0x0\n\t"
      "s_load_dwordx16 s[52:67], s[30:31], 0x40\n\t"
      "s_load_dword s28, s[30:31], 0x100\n\t"
      // ---- x interleaved: dim d -> v[16+2d] (px0), v[17+2d] (px1).
      "v_mov_b32 v8, %[xlo]\n\t"
      "v_mov_b32 v9, %[xhi]\n\t"
      XLD2(16,17)   XLD2(18,19)   XLD2(20,21)   XLD2(22,23)
      XLD2(24,25)   XLD2(26,27)   XLD2(28,29)   XLD2(30,31)
      XLD2(32,33)   XLD2(34,35)   XLD2(36,37)   XLD2(38,39)
      XLD2(40,41)   XLD2(42,43)   XLD2(44,45)   XLD2(46,47)
      XLD2(48,49)   XLD2(50,51)   XLD2(52,53)   XLD2(54,55)
      XLD2(56,57)   XLD2(58,59)   XLD2(60,61)   XLD2(62,63)
      XLD2(64,65)   XLD2(66,67)   XLD2(68,69)   XLD2(70,71)
      XLD2(72,73)   XLD2(74,75)   XLD2(76,77)   XLD2(78,79)
      XLD2(80,81)   XLD2(82,83)   XLD2(84,85)   XLD2(86,87)
      XLD2(88,89)   XLD2(90,91)   XLD2(92,93)   XLD2(94,95)
      XLD2(96,97)   XLD2(98,99)   XLD2(100,101) XLD2(102,103)
      XLD2(104,105) XLD2(106,107) XLD2(108,109) XLD2(110,111)
      XLD2(112,113) XLD2(114,115) XLD2(116,117) XLD2(118,119)
      XLD2(120,121) XLD2(122,123) XLD2(124,125) XLD2(126,127)
      XLD2(128,129) XLD2(130,131) XLD2(132,133) XLD2(134,135)
      XLD2(136,137) XLD2(138,139) XLD2(140,141) XLD2(142,143)
      "s_waitcnt vmcnt(0)\n\t"               // x + this wave's staging done
      "s_barrier\n\t"                        // all waves' staging visible
      // ---- Sx pair -> v[10:11] (packed; per-half = prior rounds' chain).
      SQ0("v[144:145]","v[16:17]") SQ0("v[146:147]","v[18:19]")
      SQ0("v[148:149]","v[20:21]") SQ0("v[150:151]","v[22:23]")
      SQ0("v[152:153]","v[24:25]") SQ0("v[154:155]","v[26:27]")
      SQ0("v[156:157]","v[28:29]") SQ0("v[158:159]","v[30:31]")
      SQA("v[144:145]","v[32:33]") SQA("v[146:147]","v[34:35]")
      SQA("v[148:149]","v[36:37]") SQA("v[150:151]","v[38:39]")
      SQA("v[152:153]","v[40:41]") SQA("v[154:155]","v[42:43]")
      SQA("v[156:157]","v[44:45]") SQA("v[158:159]","v[46:47]")
      SQA("v[144:145]","v[48:49]") SQA("v[146:147]","v[50:51]")
      SQA("v[148:149]","v[52:53]") SQA("v[150:151]","v[54:55]")
      SQA("v[152:153]","v[56:57]") SQA("v[154:155]","v[58:59]")
      SQA("v[156:157]","v[60:61]") SQA("v[158:159]","v[62:63]")
      SQA("v[144:145]","v[64:65]") SQA("v[146:147]","v[66:67]")
      SQA("v[148:149]","v[68:69]") SQA("v[150:151]","v[70:71]")
      SQA("v[152:153]","v[72:73]") SQA("v[154:155]","v[74:75]")
      SQA("v[156:157]","v[76:77]") SQA("v[158:159]","v[78:79]")
      SQA("v[144:145]","v[80:81]") SQA("v[146:147]","v[82:83]")
      SQA("v[148:149]","v[84:85]") SQA("v[150:151]","v[86:87]")
      SQA("v[152:153]","v[88:89]") SQA("v[154:155]","v[90:91]")
      SQA("v[156:157]","v[92:93]") SQA("v[158:159]","v[94:95]")
      SQA("v[144:145]","v[96:97]") SQA("v[146:147]","v[98:99]")
      SQA("v[148:149]","v[100:101]") SQA("v[150:151]","v[102:103]")
      SQA("v[152:153]","v[104:105]") SQA("v[154:155]","v[106:107]")
      SQA("v[156:157]","v[108:109]") SQA("v[158:159]","v[110:111]")
      SQA("v[144:145]","v[112:113]") SQA("v[146:147]","v[114:115]")
      SQA("v[148:149]","v[116:117]") SQA("v[150:151]","v[118:119]")
      SQA("v[152:153]","v[120:121]") SQA("v[154:155]","v[122:123]")
      SQA("v[156:157]","v[124:125]") SQA("v[158:159]","v[126:127]")
      SQA("v[144:145]","v[128:129]") SQA("v[146:147]","v[130:131]")
      SQA("v[148:149]","v[132:133]") SQA("v[150:151]","v[134:135]")
      SQA("v[152:153]","v[136:137]") SQA("v[154:155]","v[138:139]")
      SQA("v[156:157]","v[140:141]") SQA("v[158:159]","v[142:143]")
      PADD("v[144:145]","v[144:145]","v[146:147]")
      PADD("v[148:149]","v[148:149]","v[150:151]")
      PADD("v[152:153]","v[152:153]","v[154:155]")
      PADD("v[156:157]","v[156:157]","v[158:159]")
      PADD("v[144:145]","v[144:145]","v[148:149]")
      PADD("v[152:153]","v[152:153]","v[156:157]")
      PADD("v[10:11]","v[144:145]","v[152:153]")
      // ---- lds slot0 <- code k0 dims 32-63; counters.
      "v_mov_b32 v7, %[k0]\n\t"
      "v_mov_b32 v6, %[lo6]\n\t"
      "ds_read_b128 v[144:147], v6 offset:0\n\t"
      "ds_read_b128 v[148:151], v6 offset:16\n\t"
      "ds_read_b128 v[152:155], v6 offset:32\n\t"
      "ds_read_b128 v[156:159], v6 offset:48\n\t"
      "ds_read_b128 v[160:163], v6 offset:64\n\t"
      "ds_read_b128 v[164:167], v6 offset:80\n\t"
      "ds_read_b128 v[168:171], v6 offset:96\n\t"
      "ds_read_b128 v[172:175], v6 offset:112\n\t"
      "s_mov_b32 s29, 128\n\t"
      "s_waitcnt lgkmcnt(0)\n\t"
      // ================= K loop: 2 codes per iteration =================
      "Lvq%=:\n\t"
      // ---- code c (A/slot0); prefetch c+1 -> B/slot1 + sc -> s34.
      "s_add_u32 s30, s30, 0x140\n\t"
      "s_addc_u32 s31, s31, 0\n\t"
      "s_load_dwordx16 s[68:83], s[30:31], 0x0\n\t"
      "s_load_dwordx16 s[84:99], s[30:31], 0x40\n\t"
      "s_load_dword s34, s[30:31], 0x100\n\t"
      "ds_read_b128 v[176:179], v6 offset:128\n\t"
      "ds_read_b128 v[180:183], v6 offset:144\n\t"
      "ds_read_b128 v[184:187], v6 offset:160\n\t"
      "ds_read_b128 v[188:191], v6 offset:176\n\t"
      "ds_read_b128 v[192:195], v6 offset:192\n\t"
      "ds_read_b128 v[196:199], v6 offset:208\n\t"
      "ds_read_b128 v[200:203], v6 offset:224\n\t"
      "ds_read_b128 v[204:207], v6 offset:240\n\t"
      PKP0("s[36:37]","v[16:17]","v[18:19]")
      PKP("s[38:39]","v[20:21]","v[22:23]")
      PKP("s[40:41]","v[24:25]","v[26:27]")
      PKP("s[42:43]","v[28:29]","v[30:31]")
      PKP("s[44:45]","v[32:33]","v[34:35]")
      PKP("s[46:47]","v[36:37]","v[38:39]")
      PKP("s[48:49]","v[40:41]","v[42:43]")
      PKP("s[50:51]","v[44:45]","v[46:47]")
      PKP("s[52:53]","v[48:49]","v[50:51]")
      PKP("s[54:55]","v[52:53]","v[54:55]")
      PKP("s[56:57]","v[56:57]","v[58:59]")
      PKP("s[58:59]","v[60:61]","v[62:63]")
      PKP("s[60:61]","v[64:65]","v[66:67]")
      PKP("s[62:63]","v[68:69]","v[70:71]")
      PKP("s[64:65]","v[72:73]","v[74:75]")
      PKP("s[66:67]","v[76:77]","v[78:79]")
      PKP("v[144:145]","v[80:81]","v[82:83]")
      PKP("v[146:147]","v[84:85]","v[86:87]")
      PKP("v[148:149]","v[88:89]","v[90:91]")
      PKP("v[150:151]","v[92:93]","v[94:95]")
      PKP("v[152:153]","v[96:97]","v[98:99]")
      PKP("v[154:155]","v[100:101]","v[102:103]")
      PKP("v[156:157]","v[104:105]","v[106:107]")
      PKP("v[158:159]","v[108:109]","v[110:111]")
      PKP("v[160:161]","v[112:113]","v[114:115]")
      PKP("v[162:163]","v[116:117]","v[118:119]")
      PKP("v[164:165]","v[120:121]","v[122:123]")
      PKP("v[166:167]","v[124:125]","v[126:127]")
      PKP("v[168:169]","v[128:129]","v[130:131]")
      PKP("v[170:171]","v[132:133]","v[134:135]")
      PKP("v[172:173]","v[136:137]","v[138:139]")
      PKP("v[174:175]","v[140:141]","v[142:143]")
      CMB("s28")
      "s_waitcnt lgkmcnt(0)\n\t"
      // ---- code c+1 (B/slot1); prefetch c+2 -> A/slot0 + sc -> s28.
      "s_add_u32 s30, s30, 0x140\n\t"
      "s_addc_u32 s31, s31, 0\n\t"
      "s_load_dwordx16 s[36:51], s[30:31], 0x0\n\t"
      "s_load_dwordx16 s[52:67], s[30:31], 0x40\n\t"
      "s_load_dword s28, s[30:31], 0x100\n\t"
      "ds_read_b128 v[144:147], v6 offset:256\n\t"
      "ds_read_b128 v[148:151], v6 offset:272\n\t"
      "ds_read_b128 v[152:155], v6 offset:288\n\t"
      "ds_read_b128 v[156:159], v6 offset:304\n\t"
      "ds_read_b128 v[160:163], v6 offset:320\n\t"
      "ds_read_b128 v[164:167], v6 offset:336\n\t"
      "ds_read_b128 v[168:171], v6 offset:352\n\t"
      "ds_read_b128 v[172:175], v6 offset:368\n\t"
      PKP0("s[68:69]","v[16:17]","v[18:19]")
      PKP("s[70:71]","v[20:21]","v[22:23]")
      PKP("s[72:73]","v[24:25]","v[26:27]")
      PKP("s[74:75]","v[28:29]","v[30:31]")
      PKP("s[76:77]","v[32:33]","v[34:35]")
      PKP("s[78:79]","v[36:37]","v[38:39]")
      PKP("s[80:81]","v[40:41]","v[42:43]")
      PKP("s[82:83]","v[44:45]","v[46:47]")
      PKP("s[84:85]","v[48:49]","v[50:51]")
      PKP("s[86:87]","v[52:53]","v[54:55]")
      PKP("s[88:89]","v[56:57]","v[58:59]")
      PKP("s[90:91]","v[60:61]","v[62:63]")
      PKP("s[92:93]","v[64:65]","v[66:67]")
      PKP("s[94:95]","v[68:69]","v[70:71]")
      PKP("s[96:97]","v[72:73]","v[74:75]")
      PKP("s[98:99]","v[76:77]","v[78:79]")
      PKP("v[176:177]","v[80:81]","v[82:83]")
      PKP("v[178:179]","v[84:85]","v[86:87]")
      PKP("v[180:181]","v[88:89]","v[90:91]")
      PKP("v[182:183]","v[92:93]","v[94:95]")
      PKP("v[184:185]","v[96:97]","v[98:99]")
      PKP("v[186:187]","v[100:101]","v[102:103]")
      PKP("v[188:189]","v[104:105]","v[106:107]")
      PKP("v[190:191]","v[108:109]","v[110:111]")
      PKP("v[192:193]","v[112:113]","v[114:115]")
      PKP("v[194:195]","v[116:117]","v[118:119]")
      PKP("v[196:197]","v[120:121]","v[122:123]")
      PKP("v[198:199]","v[124:125]","v[126:127]")
      PKP("v[200:201]","v[128:129]","v[130:131]")
      PKP("v[202:203]","v[132:133]","v[134:135]")
      PKP("v[204:205]","v[136:137]","v[138:139]")
      PKP("v[206:207]","v[140:141]","v[142:143]")
      CMB("s34")
      "v_add_u32 v6, 0x100, v6\n\t"
      "s_sub_u32 s29, s29, 1\n\t"
      "s_waitcnt lgkmcnt(0)\n\t"
      "s_cmp_lg_u32 s29, 0\n\t"
      "s_cbranch_scc1 Lvq%=\n\t"
      : [m0] "+v"(m0), [b0] "+v"(b0), [m1] "+v"(m1), [b1] "+v"(b1)
      : [xlo] "v"(xlo), [xhi] "v"(xhi), [rw] "s"(rowa), [k0] "s"(k0s),
        [lo6] "v"(ldsoff)
      : "vcc", "scc",
        "s28","s29","s30","s31","s34",
        "s36","s37","s38","s39","s40","s41","s42","s43",
        "s44","s45","s46","s47","s48","s49","s50","s51",
        "s52","s53","s54","s55","s56","s57","s58","s59",
        "s60","s61","s62","s63","s64","s65","s66","s67",
        "s68","s69","s70","s71","s72","s73","s74","s75",
        "s76","s77","s78","s79","s80","s81","s82","s83",
        "s84","s85","s86","s87","s88","s89","s90","s91",
        "s92","s93","s94","s95","s96","s97","s98","s99",
        "v6","v7","v8","v9","v10","v11","v12","v13",
        "v16","v17","v18","v19","v20","v21","v22","v23",
        "v24","v25","v26","v27","v28","v29","v30","v31",
        "v32","v33","v34","v35","v36","v37","v38","v39",
        "v40","v41","v42","v43","v44","v45","v46","v47",
        "v48","v49","v50","v51","v52","v53","v54","v55",
        "v56","v57","v58","v59","v60","v61","v62","v63",
        "v64","v65","v66","v67","v68","v69","v70","v71",
        "v72","v73","v74","v75","v76","v77","v78","v79",
        "v80","v81","v82","v83","v84","v85","v86","v87",
        "v88","v89","v90","v91","v92","v93","v94","v95",
        "v96","v97","v98","v99","v100","v101","v102","v103",
        "v104","v105","v106","v107","v108","v109","v110","v111",
        "v112","v113","v114","v115","v116","v117","v118","v119",
        "v120","v121","v122","v123","v124","v125","v126","v127",
        "v128","v129","v130","v131","v132","v133","v134","v135",
        "v136","v137","v138","v139","v140","v141","v142","v143",
        "v144","v145","v146","v147","v148","v149","v150","v151",
        "v152","v153","v154","v155","v156","v157","v158","v159",
        "v160","v161","v162","v163","v164","v165","v166","v167",
        "v168","v169","v170","v171","v172","v173","v174","v175",
        "v176","v177","v178","v179","v180","v181","v182","v183",
        "v184","v185","v186","v187","v188","v189","v190","v191",
        "v192","v193","v194","v195","v196","v197","v198","v199",
        "v200","v201","v202","v203","v204","v205","v206","v207");

    // ---- Cross-half argmin: khalf=1 wave publishes; khalf=0 combines with
    // strict '<' (tie keeps low half's lower index = np.argmin).
    if (khalf) {
      him[p0] = m0; hii[p0] = b0;
      him[p1] = m1; hii[p1] = b1;
    }
    __syncthreads();

    float lossp = 0.f;
    if (!khalf) {
      { const float mh = him[p0]; const int ih = hii[p0];
        if (mh < m0) { m0 = mh; b0 = ih; } }
      { const float mh = him[p1]; const int ih = hii[p1];
        if (mh < m1) { m1 = mh; b1 = ih; } }
      idx_out[g0 + p0] = (float)b0;
      idx_out[g0 + p1] = (float)b1;
      float* op = out + (size_t)b * (ND * NHW) + hw0;
      const float* q0 = cb + (size_t)b0 * ND;
      const float* q1 = cb + (size_t)b1 * ND;
#pragma unroll
      for (int dq = 0; dq < 16; ++dq) {
        const f4 qa = *(const f4*)(q0 + dq * 4);
        const f4 qb = *(const f4*)(q1 + dq * 4);
        op[(size_t)(dq * 4 + 0) * NHW] = qa[0];
        op[(size_t)(dq * 4 + 1) * NHW] = qa[1];
        op[(size_t)(dq * 4 + 2) * NHW] = qa[2];
        op[(size_t)(dq * 4 + 3) * NHW] = qa[3];
        op[(size_t)(dq * 4 + 0) * NHW + 64] = qb[0];
        op[(size_t)(dq * 4 + 1) * NHW + 64] = qb[1];
        op[(size_t)(dq * 4 + 2) * NHW + 64] = qb[2];
        op[(size_t)(dq * 4 + 3) * NHW + 64] = qb[3];
      }
      lossp = m0 + m1;   // min d2 == ||x - q||^2 (within ~1e-5 rounding)
    }
#pragma unroll
    for (int off = 32; off; off >>= 1) lossp += __shfl_down(lossp, off);
    if (lane == 0 && !khalf) red[wv] = lossp;
    __syncthreads();
    if (tid == 0) {
      float t = (red[0] + red[2]) * (1.f / 8388608.f);
      atomicAdd(losses + 0, t);   // dictionary_loss
      atomicAdd(losses + 1, t);   // commitment_loss (identical forward value)
    }
  }
}

extern "C" void kernel_launch(void* const* d_in, const int* in_sizes, int n_in,
                              void* d_out, int out_size, void* d_ws, size_t ws_size,
                              hipStream_t stream) {
  const float* x  = (const float*)d_in[0];   // [32,64,64,64] fp32
  const float* cb = (const float*)d_in[1];   // [512,64] fp32
  float* out     = (float*)d_out;            // quantized [B,D,H,W]
  float* idx_out = out + OUT_ELEMS;          // indices (as fp32) [B,H,W]
  float* losses  = idx_out + NPIX;           // 2 scalars
  (void)d_ws; (void)ws_size;                 // packed tables live in module globals

  vq_prep<<<2, 256, 0, stream>>>(cb, losses);
  vq_main<<<NPIX / 256, 256, 0, stream>>>(x, cb, out, idx_out, losses);
}

// Round 12
// 175.745 us; speedup vs baseline: 3.1153x; 1.0168x over previous
//
#include <hip/hip_runtime.h>

#define NK 512
#define ND 64
#define NHW 4096
#define NPIX 131072            // 32*64*64
#define OUT_ELEMS 8388608      // 32*64*64*64
#define RS 80                  // cbp row stride (floats): 64 data + sc + 15 pad

typedef float f4 __attribute__((ext_vector_type(4)));

// cbp: row k = {cb[k][0..63], sc, pad}, 513 rows (row 512 = phantom prefetch
// target). SMEM streams dims 0-35 + sc from here.
__device__ __attribute__((aligned(64))) float cbp[513 * RS];
// cbp2: row k = {cb[k][36..63]} stride 28 floats (112 B). Staged to LDS once
// per block; uniform ds_read_b128 x7 per code in the K loop.
__device__ __attribute__((aligned(64))) float cbp2[NK * 28];

// ---------------------------------------------------------------------------
// Prep: pack cbp + cbp2 (+ sc = numpy-pairwise-8 fp32 sum of fl(c_d^2));
// zero the loss slots (harness re-poisons d_out/d_ws every replay).
// ---------------------------------------------------------------------------
__global__ __launch_bounds__(256) void vq_prep(const float* __restrict__ cb,
                                               float* __restrict__ losses) {
#pragma clang fp contract(off)
  {
    const int k = blockIdx.x * 256 + threadIdx.x;   // grid 2*256 = 512
    const float* c = cb + (size_t)k * ND;
    float* dst = cbp + (size_t)k * RS;
    float* dst2 = cbp2 + (size_t)k * 28;

    f4 v[16];
#pragma unroll
    for (int dq = 0; dq < 16; ++dq) {
      v[dq] = *(const f4*)(c + dq * 4);
      *(f4*)(dst + dq * 4) = v[dq];
      if (dq >= 9) *(f4*)(dst2 + (dq - 9) * 4) = v[dq];   // dims 36..63
    }
    float rr[8];
    rr[0] = v[0][0] * v[0][0]; rr[1] = v[0][1] * v[0][1];
    rr[2] = v[0][2] * v[0][2]; rr[3] = v[0][3] * v[0][3];
    rr[4] = v[1][0] * v[1][0]; rr[5] = v[1][1] * v[1][1];
    rr[6] = v[1][2] * v[1][2]; rr[7] = v[1][3] * v[1][3];
#pragma unroll
    for (int i = 2; i < 16; i += 2) {
      rr[0] += v[i][0] * v[i][0];     rr[1] += v[i][1] * v[i][1];
      rr[2] += v[i][2] * v[i][2];     rr[3] += v[i][3] * v[i][3];
      rr[4] += v[i + 1][0] * v[i + 1][0]; rr[5] += v[i + 1][1] * v[i + 1][1];
      rr[6] += v[i + 1][2] * v[i + 1][2]; rr[7] += v[i + 1][3] * v[i + 1][3];
    }
    dst[64] = ((rr[0] + rr[1]) + (rr[2] + rr[3])) + ((rr[4] + rr[5]) + (rr[6] + rr[7]));
    if (k < 2) losses[k] = 0.f;
  }
}

// ---- asm building blocks -------------------------------------------------
// x pair load: dim d of pixel0 -> even reg, pixel1 (px+64, +256 B) -> odd reg.
#define XLD2(V0, V1)                                             \
  "global_load_dword v" #V0 ", v[8:9], off\n\t"                  \
  "global_load_dword v" #V1 ", v[8:9], off offset:256\n\t"       \
  "v_add_co_u32 v8, vcc, 0x4000, v8\n\t"                         \
  "v_addc_co_u32 v9, vcc, 0, v9, vcc\n\t"
// Packed FMA: lo half = pixel0 chain, hi half = pixel1 chain; codebook value
// broadcast from the LO (even dim) or HI (odd dim) half of an aligned pair.
// Each pixel's d=0..63 sequential fp32 chain is preserved bit-identically.
#define PKE(CP, XP) "v_pk_fma_f32 v[12:13], " CP ", " XP ", v[12:13] op_sel:[0,0,0] op_sel_hi:[0,1,1]\n\t"
#define PKO(CP, XP) "v_pk_fma_f32 v[12:13], " CP ", " XP ", v[12:13] op_sel:[1,0,0] op_sel_hi:[1,1,1]\n\t"
#define PKP(CP, XE, XO)  PKE(CP, XE) PKO(CP, XO)
#define PKP0(CP, XE, XO)                                         \
  "v_pk_mul_f32 v[12:13], " CP ", " XE " op_sel:[0,0] op_sel_hi:[0,1]\n\t" \
  PKO(CP, XO)
// Sx: packed squares (lo=px0, hi=px1), per-half order = prior rounds.
#define SQ0(P, X) "v_pk_mul_f32 " P ", " X ", " X "\n\t"
#define SQA(P, X) "v_pk_fma_f32 " P ", " X ", " X ", " P "\n\t"
#define PADD(D, A, B) "v_pk_add_f32 " D ", " A ", " B "\n\t"
// combine: d2 = fma(acc,-2,Sx) + sc; keep-old on >=, take-new on strict <.
#define CMB(SCS)                                                 \
  "v_fma_f32 v8, v12, -2.0, v10\n\t"                             \
  "v_fma_f32 v9, v13, -2.0, v11\n\t"                             \
  "v_add_f32 v8, " SCS ", v8\n\t"                                \
  "v_add_f32 v9, " SCS ", v9\n\t"                                \
  "v_cmp_ge_f32 vcc, v8, %[m0]\n\t"                              \
  "v_cndmask_b32 %[b0], v7, %[b0], vcc\n\t"                      \
  "v_cndmask_b32 %[m0], v8, %[m0], vcc\n\t"                      \
  "v_cmp_ge_f32 vcc, v9, %[m1]\n\t"                              \
  "v_cndmask_b32 %[b1], v7, %[b1], vcc\n\t"                      \
  "v_cndmask_b32 %[m1], v9, %[m1], vcc\n\t"                      \
  "v_add_u32 v7, 1, v7\n\t"

typedef const __attribute__((address_space(1))) unsigned int gu32;
typedef __attribute__((address_space(3))) unsigned int su32;

// ---------------------------------------------------------------------------
// Main: lane = 2 pixels, hybrid delivery (R11 structure). R11 accounting:
// wall 1048 cyc/code/SIMD; VALU 671 (512 pure pk-FMA -- pk_fma is full
// peak-FLOP-rate at 4 cyc/wave64 -- + 160 CMB/loop); LDS 8 reads x 12 cyc x
// 8 waves = 768 cyc/CU/code = largest pipe. R12 rebalances the split to the
// SGPR-file maximum: SMEM carries dims 0-35 + sc (x16+x16+x4+dword = 4 reqs,
// 160 B/code -- R9's failure was 260 B), LDS carries dims 36-63 (7 b128,
// table 56 KB). LDS pipe 768 -> 672 ~= VALU 671: pipes balanced.
// Regs: v6 lds addr | v7 code ctr | v8:9 x addr then d2 | v[10:11] Sx pair |
// v[12:13] acc pair | v16-143 x interleaved (dim d -> v[16+2d],v[17+2d]) |
// v144-171 slot0 | v176-203 slot1.
// SGPRs: s24-s59 A (dims 0-35), s60-s95 B | s[96:97] row addr | s98 ctr |
// s99 scA | s100 scB.
// Geometry: 512 blocks x 256 thr; wv>>1 selects pixel group, khalf=wv&1
// selects code half; 2 blocks/CU, 2 waves/SIMD.
// Numerics bit-identical to R11 (passed): per-pixel sequential fp32 FMA
// chain d=0..63 (dims 32-35 move from VGPR-pair to SGPR-pair operands --
// same values, same chain position); d2 = fma(acc,-2,Sx)+sc; Sx/sc
// pairwise-8; ascending codes, keep-old on >=; cross-half tie keeps low
// half = np.argmin. Loss = m.
// ---------------------------------------------------------------------------
__global__ __launch_bounds__(256, 2) void vq_main(const float* __restrict__ x,
                                                  const float* __restrict__ cb,
                                                  float* __restrict__ out,
                                                  float* __restrict__ idx_out,
                                                  float* __restrict__ losses) {
#pragma clang fp contract(off)
  {
    // [0, 57344): staged cbp2 (512 x 112 B); [57344, 57456): phantom row;
    // [57456, 58480): him; [58480, 59504): hii; [59504, 59520): red.
    __shared__ __attribute__((aligned(16))) char smem[59520];
    float* him = (float*)(smem + 57456);
    int*   hii = (int*)(smem + 58480);
    float* red = (float*)(smem + 59504);

    const int tid = threadIdx.x;
    const int wv = tid >> 6;                 // 0..3
    const int lane = tid & 63;
    const int khalf = wv & 1;                // 0: codes 0-255, 1: 256-511
    const int p0 = ((wv >> 1) << 7) | lane;  // local pixel
    const int p1 = p0 + 64;
    const int g0 = blockIdx.x * 256;
    const int b = g0 >> 12;
    const int hw0 = (g0 & 4095) + p0;

    // ---- Stage cbp2 -> LDS (56 KB, 14 x 1 KB chunks per wave).
#pragma unroll
    for (int i = 0; i < 14; ++i) {
      const int off = (wv + 4 * i) << 10;
      __builtin_amdgcn_global_load_lds(
          (gu32*)((const char*)cbp2 + off + lane * 16),
          (su32*)(smem + off), 16, 0, 0);
    }

    const unsigned long long xa =
        (unsigned long long)(const void*)(x + (size_t)b * (ND * NHW) + hw0);
    const unsigned int xlo = (unsigned int)xa;
    const unsigned int xhi = (unsigned int)(xa >> 32);

    const int k0 = khalf << 8;               // wave-uniform
    const unsigned long long ra =
        (unsigned long long)(const void*)cbp + (unsigned long long)k0 * (RS * 4);
    const unsigned int rlo = __builtin_amdgcn_readfirstlane((unsigned int)ra);
    const unsigned int rhi = __builtin_amdgcn_readfirstlane((unsigned int)(ra >> 32));
    const unsigned long long rowa = ((unsigned long long)rhi << 32) | rlo;
    const int k0s = __builtin_amdgcn_readfirstlane(k0);
    const unsigned int ldsoff = (unsigned int)khalf * 28672u;

    float m0 = 3.0e38f, m1 = 3.0e38f;
    int b0 = 0, b1 = 0;

    asm volatile(
      // ---- smem A <- code k0 dims 0-35 + sc (overlaps x load + Sx).
      "s_mov_b64 s[96:97], %[rw]\n\t"
      "s_load_dwordx16 s[24:39], s[96:97], 0x0\n\t"
      "s_load_dwordx16 s[40:55], s[96:97], 0x40\n\t"
      "s_load_dwordx4  s[56:59], s[96:97], 0x80\n\t"
      "s_load_dword    s99,      s[96:97], 0x100\n\t"
      // ---- x interleaved: dim d -> v[16+2d] (px0), v[17+2d] (px1).
      "v_mov_b32 v8, %[xlo]\n\t"
      "v_mov_b32 v9, %[xhi]\n\t"
      XLD2(16,17)   XLD2(18,19)   XLD2(20,21)   XLD2(22,23)
      XLD2(24,25)   XLD2(26,27)   XLD2(28,29)   XLD2(30,31)
      XLD2(32,33)   XLD2(34,35)   XLD2(36,37)   XLD2(38,39)
      XLD2(40,41)   XLD2(42,43)   XLD2(44,45)   XLD2(46,47)
      XLD2(48,49)   XLD2(50,51)   XLD2(52,53)   XLD2(54,55)
      XLD2(56,57)   XLD2(58,59)   XLD2(60,61)   XLD2(62,63)
      XLD2(64,65)   XLD2(66,67)   XLD2(68,69)   XLD2(70,71)
      XLD2(72,73)   XLD2(74,75)   XLD2(76,77)   XLD2(78,79)
      XLD2(80,81)   XLD2(82,83)   XLD2(84,85)   XLD2(86,87)
      XLD2(88,89)   XLD2(90,91)   XLD2(92,93)   XLD2(94,95)
      XLD2(96,97)   XLD2(98,99)   XLD2(100,101) XLD2(102,103)
      XLD2(104,105) XLD2(106,107) XLD2(108,109) XLD2(110,111)
      XLD2(112,113) XLD2(114,115) XLD2(116,117) XLD2(118,119)
      XLD2(120,121) XLD2(122,123) XLD2(124,125) XLD2(126,127)
      XLD2(128,129) XLD2(130,131) XLD2(132,133) XLD2(134,135)
      XLD2(136,137) XLD2(138,139) XLD2(140,141) XLD2(142,143)
      "s_waitcnt vmcnt(0)\n\t"               // x + this wave's staging done
      "s_barrier\n\t"                        // all waves' staging visible
      // ---- Sx pair -> v[10:11] (packed; per-half = prior rounds' chain).
      SQ0("v[144:145]","v[16:17]") SQ0("v[146:147]","v[18:19]")
      SQ0("v[148:149]","v[20:21]") SQ0("v[150:151]","v[22:23]")
      SQ0("v[152:153]","v[24:25]") SQ0("v[154:155]","v[26:27]")
      SQ0("v[156:157]","v[28:29]") SQ0("v[158:159]","v[30:31]")
      SQA("v[144:145]","v[32:33]") SQA("v[146:147]","v[34:35]")
      SQA("v[148:149]","v[36:37]") SQA("v[150:151]","v[38:39]")
      SQA("v[152:153]","v[40:41]") SQA("v[154:155]","v[42:43]")
      SQA("v[156:157]","v[44:45]") SQA("v[158:159]","v[46:47]")
      SQA("v[144:145]","v[48:49]") SQA("v[146:147]","v[50:51]")
      SQA("v[148:149]","v[52:53]") SQA("v[150:151]","v[54:55]")
      SQA("v[152:153]","v[56:57]") SQA("v[154:155]","v[58:59]")
      SQA("v[156:157]","v[60:61]") SQA("v[158:159]","v[62:63]")
      SQA("v[144:145]","v[64:65]") SQA("v[146:147]","v[66:67]")
      SQA("v[148:149]","v[68:69]") SQA("v[150:151]","v[70:71]")
      SQA("v[152:153]","v[72:73]") SQA("v[154:155]","v[74:75]")
      SQA("v[156:157]","v[76:77]") SQA("v[158:159]","v[78:79]")
      SQA("v[144:145]","v[80:81]") SQA("v[146:147]","v[82:83]")
      SQA("v[148:149]","v[84:85]") SQA("v[150:151]","v[86:87]")
      SQA("v[152:153]","v[88:89]") SQA("v[154:155]","v[90:91]")
      SQA("v[156:157]","v[92:93]") SQA("v[158:159]","v[94:95]")
      SQA("v[144:145]","v[96:97]") SQA("v[146:147]","v[98:99]")
      SQA("v[148:149]","v[100:101]") SQA("v[150:151]","v[102:103]")
      SQA("v[152:153]","v[104:105]") SQA("v[154:155]","v[106:107]")
      SQA("v[156:157]","v[108:109]") SQA("v[158:159]","v[110:111]")
      SQA("v[144:145]","v[112:113]") SQA("v[146:147]","v[114:115]")
      SQA("v[148:149]","v[116:117]") SQA("v[150:151]","v[118:119]")
      SQA("v[152:153]","v[120:121]") SQA("v[154:155]","v[122:123]")
      SQA("v[156:157]","v[124:125]") SQA("v[158:159]","v[126:127]")
      SQA("v[144:145]","v[128:129]") SQA("v[146:147]","v[130:131]")
      SQA("v[148:149]","v[132:133]") SQA("v[150:151]","v[134:135]")
      SQA("v[152:153]","v[136:137]") SQA("v[154:155]","v[138:139]")
      SQA("v[156:157]","v[140:141]") SQA("v[158:159]","v[142:143]")
      PADD("v[144:145]","v[144:145]","v[146:147]")
      PADD("v[148:149]","v[148:149]","v[150:151]")
      PADD("v[152:153]","v[152:153]","v[154:155]")
      PADD("v[156:157]","v[156:157]","v[158:159]")
      PADD("v[144:145]","v[144:145]","v[148:149]")
      PADD("v[152:153]","v[152:153]","v[156:157]")
      PADD("v[10:11]","v[144:145]","v[152:153]")
      // ---- lds slot0 <- code k0 dims 36-63; counters.
      "v_mov_b32 v7, %[k0]\n\t"
      "v_mov_b32 v6, %[lo6]\n\t"
      "ds_read_b128 v[144:147], v6 offset:0\n\t"
      "ds_read_b128 v[148:151], v6 offset:16\n\t"
      "ds_read_b128 v[152:155], v6 offset:32\n\t"
      "ds_read_b128 v[156:159], v6 offset:48\n\t"
      "ds_read_b128 v[160:163], v6 offset:64\n\t"
      "ds_read_b128 v[164:167], v6 offset:80\n\t"
      "ds_read_b128 v[168:171], v6 offset:96\n\t"
      "s_mov_b32 s98, 128\n\t"
      "s_waitcnt lgkmcnt(0)\n\t"
      // ================= K loop: 2 codes per iteration =================
      "Lvq%=:\n\t"
      // ---- code c (A/slot0); prefetch c+1 -> B/slot1 + sc -> s100.
      "s_add_u32 s96, s96, 0x140\n\t"
      "s_addc_u32 s97, s97, 0\n\t"
      "s_load_dwordx16 s[60:75], s[96:97], 0x0\n\t"
      "s_load_dwordx16 s[76:91], s[96:97], 0x40\n\t"
      "s_load_dwordx4  s[92:95], s[96:97], 0x80\n\t"
      "s_load_dword    s100,     s[96:97], 0x100\n\t"
      "ds_read_b128 v[176:179], v6 offset:112\n\t"
      "ds_read_b128 v[180:183], v6 offset:128\n\t"
      "ds_read_b128 v[184:187], v6 offset:144\n\t"
      "ds_read_b128 v[188:191], v6 offset:160\n\t"
      "ds_read_b128 v[192:195], v6 offset:176\n\t"
      "ds_read_b128 v[196:199], v6 offset:192\n\t"
      "ds_read_b128 v[200:203], v6 offset:208\n\t"
      PKP0("s[24:25]","v[16:17]","v[18:19]")
      PKP("s[26:27]","v[20:21]","v[22:23]")
      PKP("s[28:29]","v[24:25]","v[26:27]")
      PKP("s[30:31]","v[28:29]","v[30:31]")
      PKP("s[32:33]","v[32:33]","v[34:35]")
      PKP("s[34:35]","v[36:37]","v[38:39]")
      PKP("s[36:37]","v[40:41]","v[42:43]")
      PKP("s[38:39]","v[44:45]","v[46:47]")
      PKP("s[40:41]","v[48:49]","v[50:51]")
      PKP("s[42:43]","v[52:53]","v[54:55]")
      PKP("s[44:45]","v[56:57]","v[58:59]")
      PKP("s[46:47]","v[60:61]","v[62:63]")
      PKP("s[48:49]","v[64:65]","v[66:67]")
      PKP("s[50:51]","v[68:69]","v[70:71]")
      PKP("s[52:53]","v[72:73]","v[74:75]")
      PKP("s[54:55]","v[76:77]","v[78:79]")
      PKP("s[56:57]","v[80:81]","v[82:83]")
      PKP("s[58:59]","v[84:85]","v[86:87]")
      PKP("v[144:145]","v[88:89]","v[90:91]")
      PKP("v[146:147]","v[92:93]","v[94:95]")
      PKP("v[148:149]","v[96:97]","v[98:99]")
      PKP("v[150:151]","v[100:101]","v[102:103]")
      PKP("v[152:153]","v[104:105]","v[106:107]")
      PKP("v[154:155]","v[108:109]","v[110:111]")
      PKP("v[156:157]","v[112:113]","v[114:115]")
      PKP("v[158:159]","v[116:117]","v[118:119]")
      PKP("v[160:161]","v[120:121]","v[122:123]")
      PKP("v[162:163]","v[124:125]","v[126:127]")
      PKP("v[164:165]","v[128:129]","v[130:131]")
      PKP("v[166:167]","v[132:133]","v[134:135]")
      PKP("v[168:169]","v[136:137]","v[138:139]")
      PKP("v[170:171]","v[140:141]","v[142:143]")
      CMB("s99")
      "s_waitcnt lgkmcnt(0)\n\t"
      // ---- code c+1 (B/slot1); prefetch c+2 -> A/slot0 + sc -> s99.
      "s_add_u32 s96, s96, 0x140\n\t"
      "s_addc_u32 s97, s97, 0\n\t"
      "s_load_dwordx16 s[24:39], s[96:97], 0x0\n\t"
      "s_load_dwordx16 s[40:55], s[96:97], 0x40\n\t"
      "s_load_dwordx4  s[56:59], s[96:97], 0x80\n\t"
      "s_load_dword    s99,      s[96:97], 0x100\n\t"
      "ds_read_b128 v[144:147], v6 offset:224\n\t"
      "ds_read_b128 v[148:151], v6 offset:240\n\t"
      "ds_read_b128 v[152:155], v6 offset:256\n\t"
      "ds_read_b128 v[156:159], v6 offset:272\n\t"
      "ds_read_b128 v[160:163], v6 offset:288\n\t"
      "ds_read_b128 v[164:167], v6 offset:304\n\t"
      "ds_read_b128 v[168:171], v6 offset:320\n\t"
      PKP0("s[60:61]","v[16:17]","v[18:19]")
      PKP("s[62:63]","v[20:21]","v[22:23]")
      PKP("s[64:65]","v[24:25]","v[26:27]")
      PKP("s[66:67]","v[28:29]","v[30:31]")
      PKP("s[68:69]","v[32:33]","v[34:35]")
      PKP("s[70:71]","v[36:37]","v[38:39]")
      PKP("s[72:73]","v[40:41]","v[42:43]")
      PKP("s[74:75]","v[44:45]","v[46:47]")
      PKP("s[76:77]","v[48:49]","v[50:51]")
      PKP("s[78:79]","v[52:53]","v[54:55]")
      PKP("s[80:81]","v[56:57]","v[58:59]")
      PKP("s[82:83]","v[60:61]","v[62:63]")
      PKP("s[84:85]","v[64:65]","v[66:67]")
      PKP("s[86:87]","v[68:69]","v[70:71]")
      PKP("s[88:89]","v[72:73]","v[74:75]")
      PKP("s[90:91]","v[76:77]","v[78:79]")
      PKP("s[92:93]","v[80:81]","v[82:83]")
      PKP("s[94:95]","v[84:85]","v[86:87]")
      PKP("v[176:177]","v[88:89]","v[90:91]")
      PKP("v[178:179]","v[92:93]","v[94:95]")
      PKP("v[180:181]","v[96:97]","v[98:99]")
      PKP("v[182:183]","v[100:101]","v[102:103]")
      PKP("v[184:185]","v[104:105]","v[106:107]")
      PKP("v[186:187]","v[108:109]","v[110:111]")
      PKP("v[188:189]","v[112:113]","v[114:115]")
      PKP("v[190:191]","v[116:117]","v[118:119]")
      PKP("v[192:193]","v[120:121]","v[122:123]")
      PKP("v[194:195]","v[124:125]","v[126:127]")
      PKP("v[196:197]","v[128:129]","v[130:131]")
      PKP("v[198:199]","v[132:133]","v[134:135]")
      PKP("v[200:201]","v[136:137]","v[138:139]")
      PKP("v[202:203]","v[140:141]","v[142:143]")
      CMB("s100")
      "v_add_u32 v6, 0xE0, v6\n\t"
      "s_sub_u32 s98, s98, 1\n\t"
      "s_waitcnt lgkmcnt(0)\n\t"
      "s_cmp_lg_u32 s98, 0\n\t"
      "s_cbranch_scc1 Lvq%=\n\t"
      : [m0] "+v"(m0), [b0] "+v"(b0), [m1] "+v"(m1), [b1] "+v"(b1)
      : [xlo] "v"(xlo), [xhi] "v"(xhi), [rw] "s"(rowa), [k0] "s"(k0s),
        [lo6] "v"(ldsoff)
      : "vcc", "scc",
        "s24","s25","s26","s27","s28","s29","s30","s31",
        "s32","s33","s34","s35","s36","s37","s38","s39",
        "s40","s41","s42","s43","s44","s45","s46","s47",
        "s48","s49","s50","s51","s52","s53","s54","s55",
        "s56","s57","s58","s59","s60","s61","s62","s63",
        "s64","s65","s66","s67","s68","s69","s70","s71",
        "s72","s73","s74","s75","s76","s77","s78","s79",
        "s80","s81","s82","s83","s84","s85","s86","s87",
        "s88","s89","s90","s91","s92","s93","s94","s95",
        "s96","s97","s98","s99","s100",
        "v6","v7","v8","v9","v10","v11","v12","v13",
        "v16","v17","v18","v19","v20","v21","v22","v23",
        "v24","v25","v26","v27","v28","v29","v30","v31",
        "v32","v33","v34","v35","v36","v37","v38","v39",
        "v40","v41","v42","v43","v44","v45","v46","v47",
        "v48","v49","v50","v51","v52","v53","v54","v55",
        "v56","v57","v58","v59","v60","v61","v62","v63",
        "v64","v65","v66","v67","v68","v69","v70","v71",
        "v72","v73","v74","v75","v76","v77","v78","v79",
        "v80","v81","v82","v83","v84","v85","v86","v87",
        "v88","v89","v90","v91","v92","v93","v94","v95",
        "v96","v97","v98","v99","v100","v101","v102","v103",
        "v104","v105","v106","v107","v108","v109","v110","v111",
        "v112","v113","v114","v115","v116","v117","v118","v119",
        "v120","v121","v122","v123","v124","v125","v126","v127",
        "v128","v129","v130","v131","v132","v133","v134","v135",
        "v136","v137","v138","v139","v140","v141","v142","v143",
        "v144","v145","v146","v147","v148","v149","v150","v151",
        "v152","v153","v154","v155","v156","v157","v158","v159",
        "v160","v161","v162","v163","v164","v165","v166","v167",
        "v168","v169","v170","v171",
        "v176","v177","v178","v179","v180","v181","v182","v183",
        "v184","v185","v186","v187","v188","v189","v190","v191",
        "v192","v193","v194","v195","v196","v197","v198","v199",
        "v200","v201","v202","v203");

    // ---- Cross-half argmin: khalf=1 wave publishes; khalf=0 combines with
    // strict '<' (tie keeps low half's lower index = np.argmin).
    if (khalf) {
      him[p0] = m0; hii[p0] = b0;
      him[p1] = m1; hii[p1] = b1;
    }
    __syncthreads();

    float lossp = 0.f;
    if (!khalf) {
      { const float mh = him[p0]; const int ih = hii[p0];
        if (mh < m0) { m0 = mh; b0 = ih; } }
      { const float mh = him[p1]; const int ih = hii[p1];
        if (mh < m1) { m1 = mh; b1 = ih; } }
      idx_out[g0 + p0] = (float)b0;
      idx_out[g0 + p1] = (float)b1;
      float* op = out + (size_t)b * (ND * NHW) + hw0;
      const float* q0 = cb + (size_t)b0 * ND;
      const float* q1 = cb + (size_t)b1 * ND;
#pragma unroll
      for (int dq = 0; dq < 16; ++dq) {
        const f4 qa = *(const f4*)(q0 + dq * 4);
        const f4 qb = *(const f4*)(q1 + dq * 4);
        op[(size_t)(dq * 4 + 0) * NHW] = qa[0];
        op[(size_t)(dq * 4 + 1) * NHW] = qa[1];
        op[(size_t)(dq * 4 + 2) * NHW] = qa[2];
        op[(size_t)(dq * 4 + 3) * NHW] = qa[3];
        op[(size_t)(dq * 4 + 0) * NHW + 64] = qb[0];
        op[(size_t)(dq * 4 + 1) * NHW + 64] = qb[1];
        op[(size_t)(dq * 4 + 2) * NHW + 64] = qb[2];
        op[(size_t)(dq * 4 + 3) * NHW + 64] = qb[3];
      }
      lossp = m0 + m1;   // min d2 == ||x - q||^2 (within ~1e-5 rounding)
    }
#pragma unroll
    for (int off = 32; off; off >>= 1) lossp += __shfl_down(lossp, off);
    if (lane == 0 && !khalf) red[wv] = lossp;
    __syncthreads();
    if (tid == 0) {
      float t = (red[0] + red[2]) * (1.f / 8388608.f);
      atomicAdd(losses + 0, t);   // dictionary_loss
      atomicAdd(losses + 1, t);   // commitment_loss (identical forward value)
    }
  }
}

extern "C" void kernel_launch(void* const* d_in, const int* in_sizes, int n_in,
                              void* d_out, int out_size, void* d_ws, size_t ws_size,
                              hipStream_t stream) {
  const float* x  = (const float*)d_in[0];   // [32,64,64,64] fp32
  const float* cb = (const float*)d_in[1];   // [512,64] fp32
  float* out     = (float*)d_out;            // quantized [B,D,H,W]
  float* idx_out = out + OUT_ELEMS;          // indices (as fp32) [B,H,W]
  float* losses  = idx_out + NPIX;           // 2 scalars
  (void)d_ws; (void)ws_size;                 // packed tables live in module globals

  vq_prep<<<2, 256, 0, stream>>>(cb, losses);
  vq_main<<<NPIX / 256, 256, 0, stream>>>(x, cb, out, idx_out, losses);
}

// Round 13
// 173.566 us; speedup vs baseline: 3.1544x; 1.0126x over previous
//
#include <hip/hip_runtime.h>

#define NK 512
#define ND 64
#define NHW 4096
#define NPIX 131072            // 32*64*64
#define OUT_ELEMS 8388608      // 32*64*64*64
#define RS 48                  // packed SMEM row stride (floats): 36 data + sc + 11 pad = 192 B

typedef float f4 __attribute__((ext_vector_type(4)));

// cbp: row k = {cb[k][0..35], sc, pad} (192 B, 3 full cache lines), 513 rows
// (row 512 = phantom prefetch target). SMEM streams x16+x16+x8 from here --
// contiguous 49 KB/half stream (R12's 320-B sparse rows = 82 KB, 4/5 lines).
__device__ __attribute__((aligned(64))) float cbp[513 * RS];
// cbp2: row k = {cb[k][36..63]} stride 28 floats (112 B). Staged to LDS once
// per block; uniform ds_read_b128 x7 per code in the K loop.
__device__ __attribute__((aligned(64))) float cbp2[NK * 28];

// ---------------------------------------------------------------------------
// Prep: pack cbp + cbp2 (+ sc = numpy-pairwise-8 fp32 sum of fl(c_d^2));
// zero the loss slots (harness re-poisons d_out/d_ws every replay).
// ---------------------------------------------------------------------------
__global__ __launch_bounds__(256) void vq_prep(const float* __restrict__ cb,
                                               float* __restrict__ losses) {
#pragma clang fp contract(off)
  {
    const int k = blockIdx.x * 256 + threadIdx.x;   // grid 2*256 = 512
    const float* c = cb + (size_t)k * ND;
    float* dst = cbp + (size_t)k * RS;
    float* dst2 = cbp2 + (size_t)k * 28;

    f4 v[16];
#pragma unroll
    for (int dq = 0; dq < 16; ++dq) {
      v[dq] = *(const f4*)(c + dq * 4);
      if (dq < 9) *(f4*)(dst + dq * 4) = v[dq];            // dims 0..35
      if (dq >= 9) *(f4*)(dst2 + (dq - 9) * 4) = v[dq];    // dims 36..63
    }
    float rr[8];
    rr[0] = v[0][0] * v[0][0]; rr[1] = v[0][1] * v[0][1];
    rr[2] = v[0][2] * v[0][2]; rr[3] = v[0][3] * v[0][3];
    rr[4] = v[1][0] * v[1][0]; rr[5] = v[1][1] * v[1][1];
    rr[6] = v[1][2] * v[1][2]; rr[7] = v[1][3] * v[1][3];
#pragma unroll
    for (int i = 2; i < 16; i += 2) {
      rr[0] += v[i][0] * v[i][0];     rr[1] += v[i][1] * v[i][1];
      rr[2] += v[i][2] * v[i][2];     rr[3] += v[i][3] * v[i][3];
      rr[4] += v[i + 1][0] * v[i + 1][0]; rr[5] += v[i + 1][1] * v[i + 1][1];
      rr[6] += v[i + 1][2] * v[i + 1][2]; rr[7] += v[i + 1][3] * v[i + 1][3];
    }
    dst[36] = ((rr[0] + rr[1]) + (rr[2] + rr[3])) + ((rr[4] + rr[5]) + (rr[6] + rr[7]));
    dst[37] = 0.f; dst[38] = 0.f; dst[39] = 0.f;   // rest of the x8 window
    if (k < 2) losses[k] = 0.f;
  }
}

// ---- asm building blocks -------------------------------------------------
// x pair load: dim d of pixel0 -> even reg, pixel1 (px+64, +256 B) -> odd reg.
#define XLD2(V0, V1)                                             \
  "global_load_dword v" #V0 ", v[8:9], off\n\t"                  \
  "global_load_dword v" #V1 ", v[8:9], off offset:256\n\t"       \
  "v_add_co_u32 v8, vcc, 0x4000, v8\n\t"                         \
  "v_addc_co_u32 v9, vcc, 0, v9, vcc\n\t"
// Packed FMA: lo half = pixel0 chain, hi half = pixel1 chain; codebook value
// broadcast from the LO (even dim) or HI (odd dim) half of an aligned pair.
// Each pixel's d=0..63 sequential fp32 chain is preserved bit-identically.
#define PKE(CP, XP) "v_pk_fma_f32 v[12:13], " CP ", " XP ", v[12:13] op_sel:[0,0,0] op_sel_hi:[0,1,1]\n\t"
#define PKO(CP, XP) "v_pk_fma_f32 v[12:13], " CP ", " XP ", v[12:13] op_sel:[1,0,0] op_sel_hi:[1,1,1]\n\t"
#define PKP(CP, XE, XO)  PKE(CP, XE) PKO(CP, XO)
#define PKP0(CP, XE, XO)                                         \
  "v_pk_mul_f32 v[12:13], " CP ", " XE " op_sel:[0,0] op_sel_hi:[0,1]\n\t" \
  PKO(CP, XO)
// Sx: packed squares (lo=px0, hi=px1), per-half order = prior rounds.
#define SQ0(P, X) "v_pk_mul_f32 " P ", " X ", " X "\n\t"
#define SQA(P, X) "v_pk_fma_f32 " P ", " X ", " X ", " P "\n\t"
#define PADD(D, A, B) "v_pk_add_f32 " D ", " A ", " B "\n\t"
// combine: d2 = fma(acc,-2,Sx) + sc; keep-old on >=, take-new on strict <.
#define CMB(SCS)                                                 \
  "v_fma_f32 v8, v12, -2.0, v10\n\t"                             \
  "v_fma_f32 v9, v13, -2.0, v11\n\t"                             \
  "v_add_f32 v8, " SCS ", v8\n\t"                                \
  "v_add_f32 v9, " SCS ", v9\n\t"                                \
  "v_cmp_ge_f32 vcc, v8, %[m0]\n\t"                              \
  "v_cndmask_b32 %[b0], v7, %[b0], vcc\n\t"                      \
  "v_cndmask_b32 %[m0], v8, %[m0], vcc\n\t"                      \
  "v_cmp_ge_f32 vcc, v9, %[m1]\n\t"                              \
  "v_cndmask_b32 %[b1], v7, %[b1], vcc\n\t"                      \
  "v_cndmask_b32 %[m1], v9, %[m1], vcc\n\t"                      \
  "v_add_u32 v7, 1, v7\n\t"

typedef const __attribute__((address_space(1))) unsigned int gu32;
typedef __attribute__((address_space(3))) unsigned int su32;

// ---------------------------------------------------------------------------
// Main: lane = 2 pixels, hybrid delivery (R12 structure). R12 post-mortem:
// LDS-shift was neutral -> LDS not binding; VALUBusy 62% (idle slots); the
// ~450 cyc/code residual is SMEM drain exposure (issue->drain = 1 FMA block
// ~550 cyc < ~900 cyc latency under load; 2-buffer rotation is the OOO-SMEM
// structural max). R13 attacks the LATENCY: dedicated packed 192-B-row SMEM
// table (contiguous 49 KB/half stream, 3 fully-consumed cache lines/row vs
// R12's 4-of-5 sparse on 320-B rows) and x4+dword collapsed into one
// s_load_dwordx8 (d32-35+sc together) -> 3 SQC requests/code (-25%).
// Regs: v6 lds addr | v7 code ctr | v8:9 x addr then d2 | v[10:11] Sx pair |
// v[12:13] acc pair | v16-143 x interleaved | v144-171 slot0 | v176-203
// slot1. SGPRs: A = s[24:39],s[40:55],s[56:63] (sc=s60); B = s[64:79],
// s[80:95],s[16:23] (sc=s20); s[96:97] row addr | s98 ctr.
// Geometry: 512 blocks x 256 thr; wv>>1 selects pixel group, khalf=wv&1
// selects code half; 2 blocks/CU, 2 waves/SIMD.
// Numerics bit-identical to R12 (passed): per-pixel sequential fp32 FMA
// chain d=0..63 (dims 32-35 change registers, not values or positions);
// d2 = fma(acc,-2,Sx)+sc; Sx/sc pairwise-8; ascending codes, keep-old on
// >=; cross-half tie keeps low half = np.argmin. Loss = m.
// ---------------------------------------------------------------------------
__global__ __launch_bounds__(256, 2) void vq_main(const float* __restrict__ x,
                                                  const float* __restrict__ cb,
                                                  float* __restrict__ out,
                                                  float* __restrict__ idx_out,
                                                  float* __restrict__ losses) {
#pragma clang fp contract(off)
  {
    // [0, 57344): staged cbp2 (512 x 112 B); [57344, 57456): phantom row;
    // [57456, 58480): him; [58480, 59504): hii; [59504, 59520): red.
    __shared__ __attribute__((aligned(16))) char smem[59520];
    float* him = (float*)(smem + 57456);
    int*   hii = (int*)(smem + 58480);
    float* red = (float*)(smem + 59504);

    const int tid = threadIdx.x;
    const int wv = tid >> 6;                 // 0..3
    const int lane = tid & 63;
    const int khalf = wv & 1;                // 0: codes 0-255, 1: 256-511
    const int p0 = ((wv >> 1) << 7) | lane;  // local pixel
    const int p1 = p0 + 64;
    const int g0 = blockIdx.x * 256;
    const int b = g0 >> 12;
    const int hw0 = (g0 & 4095) + p0;

    // ---- Stage cbp2 -> LDS (56 KB, 14 x 1 KB chunks per wave).
#pragma unroll
    for (int i = 0; i < 14; ++i) {
      const int off = (wv + 4 * i) << 10;
      __builtin_amdgcn_global_load_lds(
          (gu32*)((const char*)cbp2 + off + lane * 16),
          (su32*)(smem + off), 16, 0, 0);
    }

    const unsigned long long xa =
        (unsigned long long)(const void*)(x + (size_t)b * (ND * NHW) + hw0);
    const unsigned int xlo = (unsigned int)xa;
    const unsigned int xhi = (unsigned int)(xa >> 32);

    const int k0 = khalf << 8;               // wave-uniform
    const unsigned long long ra =
        (unsigned long long)(const void*)cbp + (unsigned long long)k0 * (RS * 4);
    const unsigned int rlo = __builtin_amdgcn_readfirstlane((unsigned int)ra);
    const unsigned int rhi = __builtin_amdgcn_readfirstlane((unsigned int)(ra >> 32));
    const unsigned long long rowa = ((unsigned long long)rhi << 32) | rlo;
    const int k0s = __builtin_amdgcn_readfirstlane(k0);
    const unsigned int ldsoff = (unsigned int)khalf * 28672u;

    float m0 = 3.0e38f, m1 = 3.0e38f;
    int b0 = 0, b1 = 0;

    asm volatile(
      // ---- smem A <- code k0 dims 0-35 + sc (overlaps x load + Sx).
      "s_mov_b64 s[96:97], %[rw]\n\t"
      "s_load_dwordx16 s[24:39], s[96:97], 0x0\n\t"
      "s_load_dwordx16 s[40:55], s[96:97], 0x40\n\t"
      "s_load_dwordx8  s[56:63], s[96:97], 0x80\n\t"
      // ---- x interleaved: dim d -> v[16+2d] (px0), v[17+2d] (px1).
      "v_mov_b32 v8, %[xlo]\n\t"
      "v_mov_b32 v9, %[xhi]\n\t"
      XLD2(16,17)   XLD2(18,19)   XLD2(20,21)   XLD2(22,23)
      XLD2(24,25)   XLD2(26,27)   XLD2(28,29)   XLD2(30,31)
      XLD2(32,33)   XLD2(34,35)   XLD2(36,37)   XLD2(38,39)
      XLD2(40,41)   XLD2(42,43)   XLD2(44,45)   XLD2(46,47)
      XLD2(48,49)   XLD2(50,51)   XLD2(52,53)   XLD2(54,55)
      XLD2(56,57)   XLD2(58,59)   XLD2(60,61)   XLD2(62,63)
      XLD2(64,65)   XLD2(66,67)   XLD2(68,69)   XLD2(70,71)
      XLD2(72,73)   XLD2(74,75)   XLD2(76,77)   XLD2(78,79)
      XLD2(80,81)   XLD2(82,83)   XLD2(84,85)   XLD2(86,87)
      XLD2(88,89)   XLD2(90,91)   XLD2(92,93)   XLD2(94,95)
      XLD2(96,97)   XLD2(98,99)   XLD2(100,101) XLD2(102,103)
      XLD2(104,105) XLD2(106,107) XLD2(108,109) XLD2(110,111)
      XLD2(112,113) XLD2(114,115) XLD2(116,117) XLD2(118,119)
      XLD2(120,121) XLD2(122,123) XLD2(124,125) XLD2(126,127)
      XLD2(128,129) XLD2(130,131) XLD2(132,133) XLD2(134,135)
      XLD2(136,137) XLD2(138,139) XLD2(140,141) XLD2(142,143)
      "s_waitcnt vmcnt(0)\n\t"               // x + this wave's staging done
      "s_barrier\n\t"                        // all waves' staging visible
      // ---- Sx pair -> v[10:11] (packed; per-half = prior rounds' chain).
      SQ0("v[144:145]","v[16:17]") SQ0("v[146:147]","v[18:19]")
      SQ0("v[148:149]","v[20:21]") SQ0("v[150:151]","v[22:23]")
      SQ0("v[152:153]","v[24:25]") SQ0("v[154:155]","v[26:27]")
      SQ0("v[156:157]","v[28:29]") SQ0("v[158:159]","v[30:31]")
      SQA("v[144:145]","v[32:33]") SQA("v[146:147]","v[34:35]")
      SQA("v[148:149]","v[36:37]") SQA("v[150:151]","v[38:39]")
      SQA("v[152:153]","v[40:41]") SQA("v[154:155]","v[42:43]")
      SQA("v[156:157]","v[44:45]") SQA("v[158:159]","v[46:47]")
      SQA("v[144:145]","v[48:49]") SQA("v[146:147]","v[50:51]")
      SQA("v[148:149]","v[52:53]") SQA("v[150:151]","v[54:55]")
      SQA("v[152:153]","v[56:57]") SQA("v[154:155]","v[58:59]")
      SQA("v[156:157]","v[60:61]") SQA("v[158:159]","v[62:63]")
      SQA("v[144:145]","v[64:65]") SQA("v[146:147]","v[66:67]")
      SQA("v[148:149]","v[68:69]") SQA("v[150:151]","v[70:71]")
      SQA("v[152:153]","v[72:73]") SQA("v[154:155]","v[74:75]")
      SQA("v[156:157]","v[76:77]") SQA("v[158:159]","v[78:79]")
      SQA("v[144:145]","v[80:81]") SQA("v[146:147]","v[82:83]")
      SQA("v[148:149]","v[84:85]") SQA("v[150:151]","v[86:87]")
      SQA("v[152:153]","v[88:89]") SQA("v[154:155]","v[90:91]")
      SQA("v[156:157]","v[92:93]") SQA("v[158:159]","v[94:95]")
      SQA("v[144:145]","v[96:97]") SQA("v[146:147]","v[98:99]")
      SQA("v[148:149]","v[100:101]") SQA("v[150:151]","v[102:103]")
      SQA("v[152:153]","v[104:105]") SQA("v[154:155]","v[106:107]")
      SQA("v[156:157]","v[108:109]") SQA("v[158:159]","v[110:111]")
      SQA("v[144:145]","v[112:113]") SQA("v[146:147]","v[114:115]")
      SQA("v[148:149]","v[116:117]") SQA("v[150:151]","v[118:119]")
      SQA("v[152:153]","v[120:121]") SQA("v[154:155]","v[122:123]")
      SQA("v[156:157]","v[124:125]") SQA("v[158:159]","v[126:127]")
      SQA("v[144:145]","v[128:129]") SQA("v[146:147]","v[130:131]")
      SQA("v[148:149]","v[132:133]") SQA("v[150:151]","v[134:135]")
      SQA("v[152:153]","v[136:137]") SQA("v[154:155]","v[138:139]")
      SQA("v[156:157]","v[140:141]") SQA("v[158:159]","v[142:143]")
      PADD("v[144:145]","v[144:145]","v[146:147]")
      PADD("v[148:149]","v[148:149]","v[150:151]")
      PADD("v[152:153]","v[152:153]","v[154:155]")
      PADD("v[156:157]","v[156:157]","v[158:159]")
      PADD("v[144:145]","v[144:145]","v[148:149]")
      PADD("v[152:153]","v[152:153]","v[156:157]")
      PADD("v[10:11]","v[144:145]","v[152:153]")
      // ---- lds slot0 <- code k0 dims 36-63; counters.
      "v_mov_b32 v7, %[k0]\n\t"
      "v_mov_b32 v6, %[lo6]\n\t"
      "ds_read_b128 v[144:147], v6 offset:0\n\t"
      "ds_read_b128 v[148:151], v6 offset:16\n\t"
      "ds_read_b128 v[152:155], v6 offset:32\n\t"
      "ds_read_b128 v[156:159], v6 offset:48\n\t"
      "ds_read_b128 v[160:163], v6 offset:64\n\t"
      "ds_read_b128 v[164:167], v6 offset:80\n\t"
      "ds_read_b128 v[168:171], v6 offset:96\n\t"
      "s_mov_b32 s98, 128\n\t"
      "s_waitcnt lgkmcnt(0)\n\t"
      // ================= K loop: 2 codes per iteration =================
      "Lvq%=:\n\t"
      // ---- code c (A/slot0); prefetch c+1 -> B/slot1.
      "s_add_u32 s96, s96, 0xC0\n\t"
      "s_addc_u32 s97, s97, 0\n\t"
      "s_load_dwordx16 s[64:79], s[96:97], 0x0\n\t"
      "s_load_dwordx16 s[80:95], s[96:97], 0x40\n\t"
      "s_load_dwordx8  s[16:23], s[96:97], 0x80\n\t"
      "ds_read_b128 v[176:179], v6 offset:112\n\t"
      "ds_read_b128 v[180:183], v6 offset:128\n\t"
      "ds_read_b128 v[184:187], v6 offset:144\n\t"
      "ds_read_b128 v[188:191], v6 offset:160\n\t"
      "ds_read_b128 v[192:195], v6 offset:176\n\t"
      "ds_read_b128 v[196:199], v6 offset:192\n\t"
      "ds_read_b128 v[200:203], v6 offset:208\n\t"
      PKP0("s[24:25]","v[16:17]","v[18:19]")
      PKP("s[26:27]","v[20:21]","v[22:23]")
      PKP("s[28:29]","v[24:25]","v[26:27]")
      PKP("s[30:31]","v[28:29]","v[30:31]")
      PKP("s[32:33]","v[32:33]","v[34:35]")
      PKP("s[34:35]","v[36:37]","v[38:39]")
      PKP("s[36:37]","v[40:41]","v[42:43]")
      PKP("s[38:39]","v[44:45]","v[46:47]")
      PKP("s[40:41]","v[48:49]","v[50:51]")
      PKP("s[42:43]","v[52:53]","v[54:55]")
      PKP("s[44:45]","v[56:57]","v[58:59]")
      PKP("s[46:47]","v[60:61]","v[62:63]")
      PKP("s[48:49]","v[64:65]","v[66:67]")
      PKP("s[50:51]","v[68:69]","v[70:71]")
      PKP("s[52:53]","v[72:73]","v[74:75]")
      PKP("s[54:55]","v[76:77]","v[78:79]")
      PKP("s[56:57]","v[80:81]","v[82:83]")
      PKP("s[58:59]","v[84:85]","v[86:87]")
      PKP("v[144:145]","v[88:89]","v[90:91]")
      PKP("v[146:147]","v[92:93]","v[94:95]")
      PKP("v[148:149]","v[96:97]","v[98:99]")
      PKP("v[150:151]","v[100:101]","v[102:103]")
      PKP("v[152:153]","v[104:105]","v[106:107]")
      PKP("v[154:155]","v[108:109]","v[110:111]")
      PKP("v[156:157]","v[112:113]","v[114:115]")
      PKP("v[158:159]","v[116:117]","v[118:119]")
      PKP("v[160:161]","v[120:121]","v[122:123]")
      PKP("v[162:163]","v[124:125]","v[126:127]")
      PKP("v[164:165]","v[128:129]","v[130:131]")
      PKP("v[166:167]","v[132:133]","v[134:135]")
      PKP("v[168:169]","v[136:137]","v[138:139]")
      PKP("v[170:171]","v[140:141]","v[142:143]")
      CMB("s60")
      "s_waitcnt lgkmcnt(0)\n\t"
      // ---- code c+1 (B/slot1); prefetch c+2 -> A/slot0.
      "s_add_u32 s96, s96, 0xC0\n\t"
      "s_addc_u32 s97, s97, 0\n\t"
      "s_load_dwordx16 s[24:39], s[96:97], 0x0\n\t"
      "s_load_dwordx16 s[40:55], s[96:97], 0x40\n\t"
      "s_load_dwordx8  s[56:63], s[96:97], 0x80\n\t"
      "ds_read_b128 v[144:147], v6 offset:224\n\t"
      "ds_read_b128 v[148:151], v6 offset:240\n\t"
      "ds_read_b128 v[152:155], v6 offset:256\n\t"
      "ds_read_b128 v[156:159], v6 offset:272\n\t"
      "ds_read_b128 v[160:163], v6 offset:288\n\t"
      "ds_read_b128 v[164:167], v6 offset:304\n\t"
      "ds_read_b128 v[168:171], v6 offset:320\n\t"
      PKP0("s[64:65]","v[16:17]","v[18:19]")
      PKP("s[66:67]","v[20:21]","v[22:23]")
      PKP("s[68:69]","v[24:25]","v[26:27]")
      PKP("s[70:71]","v[28:29]","v[30:31]")
      PKP("s[72:73]","v[32:33]","v[34:35]")
      PKP("s[74:75]","v[36:37]","v[38:39]")
      PKP("s[76:77]","v[40:41]","v[42:43]")
      PKP("s[78:79]","v[44:45]","v[46:47]")
      PKP("s[80:81]","v[48:49]","v[50:51]")
      PKP("s[82:83]","v[52:53]","v[54:55]")
      PKP("s[84:85]","v[56:57]","v[58:59]")
      PKP("s[86:87]","v[60:61]","v[62:63]")
      PKP("s[88:89]","v[64:65]","v[66:67]")
      PKP("s[90:91]","v[68:69]","v[70:71]")
      PKP("s[92:93]","v[72:73]","v[74:75]")
      PKP("s[94:95]","v[76:77]","v[78:79]")
      PKP("s[16:17]","v[80:81]","v[82:83]")
      PKP("s[18:19]","v[84:85]","v[86:87]")
      PKP("v[176:177]","v[88:89]","v[90:91]")
      PKP("v[178:179]","v[92:93]","v[94:95]")
      PKP("v[180:181]","v[96:97]","v[98:99]")
      PKP("v[182:183]","v[100:101]","v[102:103]")
      PKP("v[184:185]","v[104:105]","v[106:107]")
      PKP("v[186:187]","v[108:109]","v[110:111]")
      PKP("v[188:189]","v[112:113]","v[114:115]")
      PKP("v[190:191]","v[116:117]","v[118:119]")
      PKP("v[192:193]","v[120:121]","v[122:123]")
      PKP("v[194:195]","v[124:125]","v[126:127]")
      PKP("v[196:197]","v[128:129]","v[130:131]")
      PKP("v[198:199]","v[132:133]","v[134:135]")
      PKP("v[200:201]","v[136:137]","v[138:139]")
      PKP("v[202:203]","v[140:141]","v[142:143]")
      CMB("s20")
      "v_add_u32 v6, 0xE0, v6\n\t"
      "s_sub_u32 s98, s98, 1\n\t"
      "s_waitcnt lgkmcnt(0)\n\t"
      "s_cmp_lg_u32 s98, 0\n\t"
      "s_cbranch_scc1 Lvq%=\n\t"
      : [m0] "+v"(m0), [b0] "+v"(b0), [m1] "+v"(m1), [b1] "+v"(b1)
      : [xlo] "v"(xlo), [xhi] "v"(xhi), [rw] "s"(rowa), [k0] "s"(k0s),
        [lo6] "v"(ldsoff)
      : "vcc", "scc",
        "s16","s17","s18","s19","s20","s21","s22","s23",
        "s24","s25","s26","s27","s28","s29","s30","s31",
        "s32","s33","s34","s35","s36","s37","s38","s39",
        "s40","s41","s42","s43","s44","s45","s46","s47",
        "s48","s49","s50","s51","s52","s53","s54","s55",
        "s56","s57","s58","s59","s60","s61","s62","s63",
        "s64","s65","s66","s67","s68","s69","s70","s71",
        "s72","s73","s74","s75","s76","s77","s78","s79",
        "s80","s81","s82","s83","s84","s85","s86","s87",
        "s88","s89","s90","s91","s92","s93","s94","s95",
        "s96","s97","s98",
        "v6","v7","v8","v9","v10","v11","v12","v13",
        "v16","v17","v18","v19","v20","v21","v22","v23",
        "v24","v25","v26","v27","v28","v29","v30","v31",
        "v32","v33","v34","v35","v36","v37","v38","v39",
        "v40","v41","v42","v43","v44","v45","v46","v47",
        "v48","v49","v50","v51","v52","v53","v54","v55",
        "v56","v57","v58","v59","v60","v61","v62","v63",
        "v64","v65","v66","v67","v68","v69","v70","v71",
        "v72","v73","v74","v75","v76","v77","v78","v79",
        "v80","v81","v82","v83","v84","v85","v86","v87",
        "v88","v89","v90","v91","v92","v93","v94","v95",
        "v96","v97","v98","v99","v100","v101","v102","v103",
        "v104","v105","v106","v107","v108","v109","v110","v111",
        "v112","v113","v114","v115","v116","v117","v118","v119",
        "v120","v121","v122","v123","v124","v125","v126","v127",
        "v128","v129","v130","v131","v132","v133","v134","v135",
        "v136","v137","v138","v139","v140","v141","v142","v143",
        "v144","v145","v146","v147","v148","v149","v150","v151",
        "v152","v153","v154","v155","v156","v157","v158","v159",
        "v160","v161","v162","v163","v164","v165","v166","v167",
        "v168","v169","v170","v171",
        "v176","v177","v178","v179","v180","v181","v182","v183",
        "v184","v185","v186","v187","v188","v189","v190","v191",
        "v192","v193","v194","v195","v196","v197","v198","v199",
        "v200","v201","v202","v203");

    // ---- Cross-half argmin: khalf=1 wave publishes; khalf=0 combines with
    // strict '<' (tie keeps low half's lower index = np.argmin).
    if (khalf) {
      him[p0] = m0; hii[p0] = b0;
      him[p1] = m1; hii[p1] = b1;
    }
    __syncthreads();

    float lossp = 0.f;
    if (!khalf) {
      { const float mh = him[p0]; const int ih = hii[p0];
        if (mh < m0) { m0 = mh; b0 = ih; } }
      { const float mh = him[p1]; const int ih = hii[p1];
        if (mh < m1) { m1 = mh; b1 = ih; } }
      idx_out[g0 + p0] = (float)b0;
      idx_out[g0 + p1] = (float)b1;
      float* op = out + (size_t)b * (ND * NHW) + hw0;
      const float* q0 = cb + (size_t)b0 * ND;
      const float* q1 = cb + (size_t)b1 * ND;
#pragma unroll
      for (int dq = 0; dq < 16; ++dq) {
        const f4 qa = *(const f4*)(q0 + dq * 4);
        const f4 qb = *(const f4*)(q1 + dq * 4);
        op[(size_t)(dq * 4 + 0) * NHW] = qa[0];
        op[(size_t)(dq * 4 + 1) * NHW] = qa[1];
        op[(size_t)(dq * 4 + 2) * NHW] = qa[2];
        op[(size_t)(dq * 4 + 3) * NHW] = qa[3];
        op[(size_t)(dq * 4 + 0) * NHW + 64] = qb[0];
        op[(size_t)(dq * 4 + 1) * NHW + 64] = qb[1];
        op[(size_t)(dq * 4 + 2) * NHW + 64] = qb[2];
        op[(size_t)(dq * 4 + 3) * NHW + 64] = qb[3];
      }
      lossp = m0 + m1;   // min d2 == ||x - q||^2 (within ~1e-5 rounding)
    }
#pragma unroll
    for (int off = 32; off; off >>= 1) lossp += __shfl_down(lossp, off);
    if (lane == 0 && !khalf) red[wv] = lossp;
    __syncthreads();
    if (tid == 0) {
      float t = (red[0] + red[2]) * (1.f / 8388608.f);
      atomicAdd(losses + 0, t);   // dictionary_loss
      atomicAdd(losses + 1, t);   // commitment_loss (identical forward value)
    }
  }
}

extern "C" void kernel_launch(void* const* d_in, const int* in_sizes, int n_in,
                              void* d_out, int out_size, void* d_ws, size_t ws_size,
                              hipStream_t stream) {
  const float* x  = (const float*)d_in[0];   // [32,64,64,64] fp32
  const float* cb = (const float*)d_in[1];   // [512,64] fp32
  float* out     = (float*)d_out;            // quantized [B,D,H,W]
  float* idx_out = out + OUT_ELEMS;          // indices (as fp32) [B,H,W]
  float* losses  = idx_out + NPIX;           // 2 scalars
  (void)d_ws; (void)ws_size;                 // packed tables live in module globals

  vq_prep<<<2, 256, 0, stream>>>(cb, losses);
  vq_main<<<NPIX / 256, 256, 0, stream>>>(x, cb, out, idx_out, losses);
}